// Round 3
// baseline (483.182 us; speedup 1.0000x reference)
//
#include <hip/hip_runtime.h>
#include <hip/hip_bf16.h>

// ---------------- problem constants ----------------
#define NI 1152
// conv2 GEMM view: M=9216 as (pos,b)=36*256; N=256 (oc); K=81 taps x 256 ic

typedef __attribute__((ext_vector_type(8))) _Float16 f16x8;
typedef __attribute__((ext_vector_type(4))) float f32x4;
typedef __attribute__((ext_vector_type(8))) unsigned short u16x8;
typedef __attribute__((ext_vector_type(4))) unsigned short u16x4;

// ws layout (bytes). Phase-1 buffers (w6,h3,wT1,pp) alias under uhat (94.4MB):
static const size_t UHAT_OFF = 0;                        // bf16 1152*10*256*16 = 94,371,840
static const size_t W6_OFF   = 0;                        // f16 81*8*16*64*8 = 10,616,832 B
static const size_t H3_OFF   = 10747904UL;               // f16 8*400*4*256*8 = 52,428,800 B
static const size_t WT1_OFF  = 63176704UL;               // f32 81*256
static const size_t PP_OFF   = 63259648UL;               // f32 9216*256 (ends 72.7MB < 94.4MB)
static const size_t U_OFF    = 94371840UL;               // f32 u[i][b][d]
static const size_t SP_OFF   = 103809024UL;              // f32 144*256*160
static const size_t L_OFF    = 127401984UL;              // f32 256*1152*10
static const size_t V_OFF    = 139198464UL;              // f32 256*160

__device__ __forceinline__ unsigned short f2bf(float x) {
    unsigned u = __builtin_bit_cast(unsigned, x);
    u += 0x7fffu + ((u >> 16) & 1u);
    return (unsigned short)(u >> 16);
}
__device__ __forceinline__ float bf2f(unsigned short h) {
    return __builtin_bit_cast(float, (unsigned)h << 16);
}
__device__ __forceinline__ void atomAddF(float* p, float v) {
    __hip_atomic_fetch_add(p, v, __ATOMIC_RELAXED, __HIP_MEMORY_SCOPE_AGENT);
}

// ---------------- weight prep: pc_w [oc][ic*81+tap] -> w6 frag-linear ----------------
// w6 linear: (((tap*8+ks)*16 + og)*64 + lane)*8 + icl
//   og=oc>>4, fr=oc&15, lane=kch*16+fr, ic=ks*32+kch*8+icl
__global__ __launch_bounds__(256) void k_prep_w(const float* __restrict__ pcw,
                                                _Float16* __restrict__ w6) {
    __shared__ float sl[5184];
    int oc  = blockIdx.x;       // 256
    int ic0 = blockIdx.y * 64;  // 4 chunks
    const float* src = pcw + (size_t)oc * 20736 + (size_t)ic0 * 81;
    for (int j = threadIdx.x; j < 5184; j += 256) sl[j] = src[j];
    __syncthreads();
    int og = oc >> 4, fr = oc & 15;
    for (int t = threadIdx.x; t < 5184; t += 256) {
        int tap = t >> 6, i = t & 63;
        int ic = ic0 + i;
        int ks = ic >> 5, kch = (ic >> 3) & 3, icl = ic & 7;
        int lane = kch * 16 + fr;
        w6[(((size_t)(tap * 8 + ks) * 16 + og) * 64 + lane) * 8 + icl] =
            (_Float16)sl[i * 81 + tap];
    }
}

// conv1_w [oc][81] -> wT1 [t][oc]
__global__ void k_transpose_w1(const float* __restrict__ w, float* __restrict__ wT) {
    int t = blockIdx.x, oc = threadIdx.x;
    wT[t * 256 + oc] = w[oc * 81 + t];
}

// ---------------- conv1 + relu -> h3[ks][y][x][p][b][8] f16 ----------------
__global__ __launch_bounds__(256) void k_conv1(const float* __restrict__ x,
                                               const float* __restrict__ wT1,
                                               const float* __restrict__ bias,
                                               _Float16* __restrict__ h3) {
    __shared__ _Float16 hs[2][20][256];  // 20KB
    int b  = blockIdx.y;    // 256
    int rp = blockIdx.x;    // 10 row-pairs
    int oc = threadIdx.x;   // 256
    int oy0 = rp * 2;
    const float* xb = x + (size_t)b * 784;
    float bv = bias[oc];
    float acc0[20], acc1[20];
#pragma unroll
    for (int i = 0; i < 20; ++i) { acc0[i] = bv; acc1[i] = bv; }
    for (int ky = 0; ky < 9; ++ky) {
        const float* r0 = xb + (oy0 + ky) * 28;
        const float* r1 = r0 + 28;
        float x0[28], x1[28];
#pragma unroll
        for (int c = 0; c < 28; ++c) { x0[c] = r0[c]; x1[c] = r1[c]; }
#pragma unroll
        for (int kx = 0; kx < 9; ++kx) {
            float w = wT1[(ky * 9 + kx) * 256 + oc];
#pragma unroll
            for (int px = 0; px < 20; ++px) {
                acc0[px] += x0[px + kx] * w;
                acc1[px] += x1[px + kx] * w;
            }
        }
    }
#pragma unroll
    for (int px = 0; px < 20; ++px) {
        hs[0][px][oc] = (_Float16)fmaxf(acc0[px], 0.f);
        hs[1][px][oc] = (_Float16)fmaxf(acc1[px], 0.f);
    }
    __syncthreads();
    for (int cid = threadIdx.x; cid < 1280; cid += 256) {
        int kp = cid & 31;          // ks*4 + p
        int pos = cid >> 5;         // ry*20 + px
        int ry = pos / 20, px2 = pos % 20;
        int ks = kp >> 2, p = kp & 3;
        f16x8 val = *(const f16x8*)&hs[ry][px2][ks * 32 + p * 8];
        _Float16* dst = h3 + ((size_t)((ks * 400 + (oy0 + ry) * 20 + px2) * 4 + p) * 256 + b) * 8;
        *(f16x8*)dst = val;
    }
}

// ---------------- primary caps conv: LDS double-buffered MFMA, 2-phase template ----------------
// grid 1152 flat; block 256 = 4 waves (2x2), block tile 128(m) x 128(n), K=81 taps x 32 ic.
// ks = blk&7 -> XCD-affinity on split-K axis (round-robin %8): per-XCD L2 set = one slice.
// Per tap: block stages A (8KB) + B (8KB) ONCE into LDS via global_load_lds(16B)
// (halves L2 read traffic vs per-wave flat loads; in-flight data rides the DMA queue,
// not VGPRs -> no register-pipeline collapse).
// T3-minimum 2-phase schedule (catalog-verified): per tap
//   { STAGE(next) ; ds_read+MFMA(cur) ; __syncthreads() ; swap }
// STAGE issued BEFORE compute so its ~200cy L2 latency hides under 16 MFMA + 8 ds_read;
// the trailing __syncthreads' vmcnt(0) drain then costs only the residual.
// No inline asm, no raw barriers (maximal-compat form of the schedule).
// LDS A layout [p(4)][bl(128)][icl(8)] linear == gll lane order; frag ds_read_b128 =
// 4 groups of 16 lanes, each 256B contiguous at 2KB stride (2-way = free, m136).
// B is a straight linear 4KB slice; frag reads are 1KB contiguous per wave.
__global__ __launch_bounds__(256, 3) void k_conv2_direct(
    const _Float16* __restrict__ h3, const _Float16* __restrict__ w6,
    float* __restrict__ pp) {
    __shared__ _Float16 Asl[2 * 4096];  // 16KB
    __shared__ _Float16 Bsl[2 * 4096];  // 16KB

    const int blk = blockIdx.x;
    const int ks = blk & 7;          // XCD = ks (round-robin %8)
    const int rest = blk >> 3;       // 0..143
    const int mt = rest % 72;
    const int nt = rest / 72;
    const int pos = mt >> 1, bhalf = mt & 1;
    const int py = pos / 6, px = pos % 6;
    const int tid = threadIdx.x;
    const int l = tid & 63;
    const int w = tid >> 6;
    const int wu = __builtin_amdgcn_readfirstlane(w);
    const int wm = w >> 1, wn = w & 1;
    const int p = l >> 4, fr = l & 15;

    // staging source pointers (per-lane). Unit u = c*256 + tid, c in {0,1}:
    //   A unit -> h3[ks][win][p=tid>>7 (+2 for c=1)][b=bhalf*128 + (tid&127)][icl]
    //   B unit -> w6[(tap*8+ks)*8192 + nt*4096 + tid*8 (+2048 for c=1)]
    const _Float16* aglb = h3 + (size_t)ks * 3276800 + (tid >> 7) * 2048 +
                           (bhalf * 128 + (tid & 127)) * 8;   // + win*8192
    const _Float16* bglb = w6 + (size_t)ks * 8192 + nt * 4096 + tid * 8;  // + tap*65536

#define STAGE(buf, aoff, boff)                                                     \
    do {                                                                           \
        const _Float16* _ga = aglb + (aoff);                                       \
        const _Float16* _gb = bglb + (boff);                                       \
        _Float16* _la = Asl + (buf) * 4096 + wu * 512;                             \
        _Float16* _lb = Bsl + (buf) * 4096 + wu * 512;                             \
        __builtin_amdgcn_global_load_lds(                                          \
            (const __attribute__((address_space(1))) void*)_ga,                    \
            (__attribute__((address_space(3))) void*)_la, 16, 0, 0);               \
        __builtin_amdgcn_global_load_lds(                                          \
            (const __attribute__((address_space(1))) void*)(_ga + 4096),           \
            (__attribute__((address_space(3))) void*)(_la + 2048), 16, 0, 0);      \
        __builtin_amdgcn_global_load_lds(                                          \
            (const __attribute__((address_space(1))) void*)_gb,                    \
            (__attribute__((address_space(3))) void*)(_lb), 16, 0, 0);             \
        __builtin_amdgcn_global_load_lds(                                          \
            (const __attribute__((address_space(1))) void*)(_gb + 2048),           \
            (__attribute__((address_space(3))) void*)(_lb + 2048), 16, 0, 0);      \
    } while (0)

    f32x4 acc[4][4];
    const f32x4 z = {0.f, 0.f, 0.f, 0.f};
#pragma unroll
    for (int mi = 0; mi < 4; ++mi)
#pragma unroll
        for (int ni = 0; ni < 4; ++ni) acc[mi][ni] = z;

#define COMPUTE(buf)                                                               \
    do {                                                                           \
        f16x8 af[4], bf[4];                                                        \
        const _Float16* _ab = Asl + (buf) * 4096 + p * 1024 + (wm * 64 + fr) * 8;  \
        const _Float16* _bb = Bsl + (buf) * 4096 + wn * 2048 + l * 8;              \
        _Pragma("unroll") for (int mi = 0; mi < 4; ++mi)                           \
            af[mi] = *(const f16x8*)(_ab + mi * 128);                              \
        _Pragma("unroll") for (int ni = 0; ni < 4; ++ni)                           \
            bf[ni] = *(const f16x8*)(_bb + ni * 512);                              \
        _Pragma("unroll") for (int mi = 0; mi < 4; ++mi)                           \
            _Pragma("unroll") for (int ni = 0; ni < 4; ++ni)                       \
                acc[mi][ni] = __builtin_amdgcn_mfma_f32_16x16x32_f16(              \
                    af[mi], bf[ni], acc[mi][ni], 0, 0, 0);                         \
    } while (0)

    // tap 0 window offset; taps walk the 9x9 window row-major over the 20x20 plane
    int win = (2 * py) * 20 + 2 * px;
    STAGE(0, (size_t)win * 8192, 0);
    __syncthreads();                      // buffer 0 ready (vmcnt drain inside)
    int wx = 0;
    size_t boff = 0;
    int buf = 0;
    for (int t = 0; t < 80; ++t) {
        // advance window to tap t+1
        if (wx == 8) { wx = 0; win += 12; } else { ++wx; win += 1; }
        boff += 65536;
        STAGE(buf ^ 1, (size_t)win * 8192, boff);  // prefetch: in flight during compute
        COMPUTE(buf);
        __syncthreads();                  // drains prefetch; reads of buf done -> safe swap
        buf ^= 1;
    }
    COMPUTE(buf);                         // tap 80
#undef STAGE
#undef COMPUTE

    // epilogue: D[m][n], m=(lane>>4)*4+reg, n=lane&15; atomic split-K reduce
    const int row0 = (l >> 4) * 4;
    const int ncol = l & 15;
#pragma unroll
    for (int mi = 0; mi < 4; ++mi)
#pragma unroll
        for (int ni = 0; ni < 4; ++ni) {
            int n = nt * 128 + wn * 64 + ni * 16 + ncol;
#pragma unroll
            for (int reg = 0; reg < 4; ++reg) {
                int m = pos * 256 + bhalf * 128 + wm * 64 + mi * 16 + row0 + reg;
                atomAddF(&pp[(size_t)m * 256 + n], acc[mi][ni][reg]);
            }
        }
}

// ---------------- bias + primary squash -> u[i][b][d]  (pp m-order = pos*256+b) ----------------
__global__ __launch_bounds__(256) void k_sum_squash2(const float* __restrict__ pp,
                                                     const float* __restrict__ bias,
                                                     float* __restrict__ u) {
    int m = blockIdx.x * 8 + (threadIdx.x >> 5);
    int cap = threadIdx.x & 31;
    const float* p0 = pp + (size_t)m * 256 + cap * 8;
    float s[8], sq = 0.f;
#pragma unroll
    for (int d = 0; d < 8; ++d) {
        float a = p0[d] + bias[cap * 8 + d];
        sq += a * a; s[d] = a;
    }
    float scale = sq / ((1.0f + sq) * sqrtf(sq + 1e-8f));
    int pos = m >> 8, b = m & 255;
    int i = cap * 36 + pos;
    float* up = u + ((size_t)i * 256 + b) * 8;
    ((float4*)up)[0] = make_float4(scale * s[0], scale * s[1], scale * s[2], scale * s[3]);
    ((float4*)up)[1] = make_float4(scale * s[4], scale * s[5], scale * s[6], scale * s[7]);
}

// ---------------- build u_hat (bf16) [i][j][b][o] ----------------
__global__ __launch_bounds__(256) void k_build_uhat(const float* __restrict__ u,
                                                    const float* __restrict__ W,
                                                    unsigned short* __restrict__ UH) {
    __shared__ float Ws[1280];
    int i = blockIdx.x;  // 1152
    for (int t = threadIdx.x; t < 1280; t += 256) Ws[t] = W[(size_t)i * 1280 + t];
    __syncthreads();
    int b = threadIdx.x;  // 256
    const float* uptr = u + ((size_t)i * 256 + b) * 8;
    float u8[8];
    ((float4*)u8)[0] = ((const float4*)uptr)[0];
    ((float4*)u8)[1] = ((const float4*)uptr)[1];
#pragma unroll
    for (int j = 0; j < 10; ++j) {
        float o16[16];
#pragma unroll
        for (int o = 0; o < 16; ++o) o16[o] = 0.f;
#pragma unroll
        for (int d = 0; d < 8; ++d) {
            const float* wp = Ws + d * 160 + j * 16;
#pragma unroll
            for (int o = 0; o < 16; ++o) o16[o] += u8[d] * wp[o];
        }
        u16x8 h0, h1;
#pragma unroll
        for (int o = 0; o < 8; ++o) { h0[o] = f2bf(o16[o]); h1[o] = f2bf(o16[8 + o]); }
        unsigned short* dst = UH + ((size_t)(i * 10 + j) * 256 + b) * 16;
        *(u16x8*)dst = h0;
        *(u16x8*)(dst + 8) = h1;
    }
}

// ---------------- routing iter 0: s0 = 0.1 * sum_i u_hat ----------------
__global__ __launch_bounds__(256) void k_route_s0(const unsigned short* __restrict__ UH,
                                                  float* __restrict__ SP) {
    int it = blockIdx.x, bt = blockIdx.y;
    int b0 = bt * 64, i0 = it * 8;
    int b_l = threadIdx.x & 63;
    int og = __builtin_amdgcn_readfirstlane((int)(threadIdx.x >> 6));
    float acc[10][4];
#pragma unroll
    for (int j = 0; j < 10; ++j)
#pragma unroll
        for (int o = 0; o < 4; ++o) acc[j][o] = 0.f;
    for (int li = 0; li < 8; ++li) {
        const unsigned short* up = UH + ((size_t)(i0 + li) * 10 * 256 + b0 + b_l) * 16 + og * 4;
#pragma unroll
        for (int j = 0; j < 10; ++j) {
            u16x4 t = *(const u16x4*)(up + j * 4096);
#pragma unroll
            for (int o = 0; o < 4; ++o) acc[j][o] += bf2f(t[o]);
        }
    }
    float* sp = SP + ((size_t)it * 256 + b0 + b_l) * 160 + og * 4;
#pragma unroll
    for (int j = 0; j < 10; ++j)
        *(float4*)(sp + j * 16) = make_float4(0.1f * acc[j][0], 0.1f * acc[j][1],
                                              0.1f * acc[j][2], 0.1f * acc[j][3]);
}

// ---------------- fused routing: logits (+)= <u_hat,v>; softmax; s-partials ----------------
// grid (144,4); block 256. add=0: L := agreement (prior logits zero). storeL: write L back.
__global__ __launch_bounds__(256) void k_route_as(float* __restrict__ L,
                                                  const unsigned short* __restrict__ UH,
                                                  const float* __restrict__ V,
                                                  float* __restrict__ SP,
                                                  int add, int storeL) {
    __shared__ float VL[64][165];
    __shared__ float LG[64][81];
    int it = blockIdx.x, bt = blockIdx.y;
    int b0 = bt * 64, i0 = it * 8;
    int b_l = threadIdx.x & 63;
    int ig = __builtin_amdgcn_readfirstlane((int)(threadIdx.x >> 6));
    int b_r = threadIdx.x >> 2, part = threadIdx.x & 3;
    {
        const float4* vsrc = (const float4*)(V + (size_t)(b0 + b_r) * 160 + part * 40);
#pragma unroll
        for (int q = 0; q < 10; ++q) {
            float4 vv = vsrc[q]; int c = part * 40 + q * 4;
            VL[b_r][c] = vv.x; VL[b_r][c + 1] = vv.y; VL[b_r][c + 2] = vv.z; VL[b_r][c + 3] = vv.w;
        }
        if (add) {
            const float4* lsrc = (const float4*)(L + (size_t)(b0 + b_r) * 11520 + i0 * 10 + part * 20);
#pragma unroll
            for (int q = 0; q < 5; ++q) {
                float4 t = lsrc[q]; int c = part * 20 + q * 4;
                LG[b_r][c] = t.x; LG[b_r][c + 1] = t.y; LG[b_r][c + 2] = t.z; LG[b_r][c + 3] = t.w;
            }
        }
    }
    __syncthreads();
    // agreement phase: thread group ig handles 2 i's
#pragma unroll
    for (int ii = 0; ii < 2; ++ii) {
        int il = ig * 2 + ii;
        int i = i0 + il;
        const unsigned short* up = UH + ((size_t)i * 10 * 256 + b0 + b_l) * 16;
#pragma unroll
        for (int j = 0; j < 10; ++j) {
            u16x8 ua = *(const u16x8*)(up + j * 4096);
            u16x8 ub = *(const u16x8*)(up + j * 4096 + 8);
            float a = 0.f;
#pragma unroll
            for (int o = 0; o < 8; ++o) a += bf2f(ua[o]) * VL[b_l][j * 16 + o];
#pragma unroll
            for (int o = 0; o < 8; ++o) a += bf2f(ub[o]) * VL[b_l][j * 16 + 8 + o];
            float base = add ? LG[b_l][il * 10 + j] : 0.f;
            LG[b_l][il * 10 + j] = base + a;
        }
    }
    __syncthreads();
    if (storeL) {
        float4* ldst = (float4*)(L + (size_t)(b0 + b_r) * 11520 + i0 * 10 + part * 20);
#pragma unroll
        for (int q = 0; q < 5; ++q) {
            int c = part * 20 + q * 4;
            ldst[q] = make_float4(LG[b_r][c], LG[b_r][c + 1], LG[b_r][c + 2], LG[b_r][c + 3]);
        }
    }
    // s phase: softmax of fresh logits, accumulate c * u_hat (og = ig reuse)
    float acc[10][4];
#pragma unroll
    for (int j = 0; j < 10; ++j)
#pragma unroll
        for (int o = 0; o < 4; ++o) acc[j][o] = 0.f;
    for (int li = 0; li < 8; ++li) {
        float lg[10];
#pragma unroll
        for (int j = 0; j < 10; ++j) lg[j] = LG[b_l][li * 10 + j];
        float m = lg[0];
#pragma unroll
        for (int j = 1; j < 10; ++j) m = fmaxf(m, lg[j]);
        float e[10], ssum = 0.f;
#pragma unroll
        for (int j = 0; j < 10; ++j) { e[j] = __expf(lg[j] - m); ssum += e[j]; }
        float inv = 1.0f / ssum;
        const unsigned short* up = UH + ((size_t)(i0 + li) * 10 * 256 + b0 + b_l) * 16 + ig * 4;
#pragma unroll
        for (int j = 0; j < 10; ++j) {
            float cj = e[j] * inv;
            u16x4 t = *(const u16x4*)(up + j * 4096);
#pragma unroll
            for (int o = 0; o < 4; ++o) acc[j][o] += cj * bf2f(t[o]);
        }
    }
    float* sp = SP + ((size_t)it * 256 + b0 + b_l) * 160 + ig * 4;
#pragma unroll
    for (int j = 0; j < 10; ++j)
        *(float4*)(sp + j * 16) = make_float4(acc[j][0], acc[j][1], acc[j][2], acc[j][3]);
}

// ---------------- routing: reduce partials + squash -> v ----------------
__global__ __launch_bounds__(256) void k_route_v(const float* __restrict__ SP,
                                                 float* __restrict__ vout) {
    int n = blockIdx.x * 256 + threadIdx.x;  // 40960
    float ssum = 0.f;
    for (int t = 0; t < 144; ++t) ssum += SP[(size_t)t * 40960 + n];
    float sq = ssum * ssum;
    float tot = sq;
#pragma unroll
    for (int mask = 1; mask < 16; mask <<= 1) tot += __shfl_xor(tot, mask, 64);
    float scale = tot / ((1.0f + tot) * sqrtf(tot + 1e-8f));
    vout[n] = scale * ssum;
}

// ---------------- launcher ----------------
extern "C" void kernel_launch(void* const* d_in, const int* in_sizes, int n_in,
                              void* d_out, int out_size, void* d_ws, size_t ws_size,
                              hipStream_t stream) {
    (void)in_sizes; (void)n_in; (void)out_size; (void)ws_size;
    const float* x   = (const float*)d_in[0];
    const float* c1w = (const float*)d_in[1];
    const float* c1b = (const float*)d_in[2];
    const float* pcw = (const float*)d_in[3];
    const float* pcb = (const float*)d_in[4];
    const float* Wd  = (const float*)d_in[5];
    float* out = (float*)d_out;
    char* wsb  = (char*)d_ws;

    unsigned short* uh = (unsigned short*)(wsb + UHAT_OFF);
    _Float16* w6 = (_Float16*)(wsb + W6_OFF);
    _Float16* h3 = (_Float16*)(wsb + H3_OFF);
    float* wT1 = (float*)(wsb + WT1_OFF);
    float* pp  = (float*)(wsb + PP_OFF);
    float* u   = (float*)(wsb + U_OFF);
    float* sp  = (float*)(wsb + SP_OFF);
    float* lg  = (float*)(wsb + L_OFF);
    float* v   = (float*)(wsb + V_OFF);

    hipMemsetAsync(pp, 0, (size_t)9216 * 256 * sizeof(float), stream);

    k_prep_w<<<dim3(256, 4), 256, 0, stream>>>(pcw, w6);
    k_transpose_w1<<<81, 256, 0, stream>>>(c1w, wT1);
    k_conv1<<<dim3(10, 256), 256, 0, stream>>>(x, wT1, c1b, h3);
    k_conv2_direct<<<dim3(1152), 256, 0, stream>>>(h3, w6, pp);
    k_sum_squash2<<<1152, 256, 0, stream>>>(pp, pcb, u);
    k_build_uhat<<<1152, 256, 0, stream>>>(u, Wd, uh);

    // iter 0: c = 0.1 exactly
    k_route_s0<<<dim3(144, 4), 256, 0, stream>>>(uh, sp);
    k_route_v<<<160, 256, 0, stream>>>(sp, v);
    // iter 1 (fused agree+softmax+s); logits were zero -> add=0, store for iter 2
    k_route_as<<<dim3(144, 4), 256, 0, stream>>>(lg, uh, v, sp, 0, 1);
    k_route_v<<<160, 256, 0, stream>>>(sp, v);
    // iter 2 (fused); last use of logits -> no store
    k_route_as<<<dim3(144, 4), 256, 0, stream>>>(lg, uh, v, sp, 1, 0);
    k_route_v<<<160, 256, 0, stream>>>(sp, out);
}

// Round 4
// 474.569 us; speedup vs baseline: 1.0181x; 1.0181x over previous
//
#include <hip/hip_runtime.h>
#include <hip/hip_bf16.h>

// ---------------- problem constants ----------------
#define NI 1152
// conv2 GEMM view: M=9216 as (pos,b)=36*256; N=256 (oc); K=81 taps x 256 ic

typedef __attribute__((ext_vector_type(8))) _Float16 f16x8;
typedef __attribute__((ext_vector_type(4))) float f32x4;
typedef __attribute__((ext_vector_type(8))) unsigned short u16x8;
typedef __attribute__((ext_vector_type(4))) unsigned short u16x4;

// ws layout (bytes). Phase-1 buffers (w6,h3,wT1,pp) alias under uhat (94.4MB):
static const size_t UHAT_OFF = 0;                        // bf16 1152*10*256*16 = 94,371,840
static const size_t W6_OFF   = 0;                        // f16 81*8*16*64*8 = 10,616,832 B
static const size_t H3_OFF   = 10747904UL;               // f16 8*400*4*256*8 = 52,428,800 B
static const size_t WT1_OFF  = 63176704UL;               // f32 81*256
static const size_t PP_OFF   = 63259648UL;               // f32 9216*256 (ends 72.7MB < 94.4MB)
static const size_t U_OFF    = 94371840UL;               // f32 u[i][b][d]
static const size_t SP_OFF   = 103809024UL;              // f32 144*256*160
static const size_t L_OFF    = 127401984UL;              // f32 256*1152*10
static const size_t V_OFF    = 139198464UL;              // f32 256*160

__device__ __forceinline__ unsigned short f2bf(float x) {
    unsigned u = __builtin_bit_cast(unsigned, x);
    u += 0x7fffu + ((u >> 16) & 1u);
    return (unsigned short)(u >> 16);
}
__device__ __forceinline__ float bf2f(unsigned short h) {
    return __builtin_bit_cast(float, (unsigned)h << 16);
}
__device__ __forceinline__ void atomAddF(float* p, float v) {
    __hip_atomic_fetch_add(p, v, __ATOMIC_RELAXED, __HIP_MEMORY_SCOPE_AGENT);
}

// ---------------- weight prep: pc_w [oc][ic*81+tap] -> w6 frag-linear ----------------
// w6 linear: (((tap*8+ks)*16 + og)*64 + lane)*8 + icl
//   og=oc>>4, fr=oc&15, lane=kch*16+fr, ic=ks*32+kch*8+icl
__global__ __launch_bounds__(256) void k_prep_w(const float* __restrict__ pcw,
                                                _Float16* __restrict__ w6) {
    __shared__ float sl[5184];
    int oc  = blockIdx.x;       // 256
    int ic0 = blockIdx.y * 64;  // 4 chunks
    const float* src = pcw + (size_t)oc * 20736 + (size_t)ic0 * 81;
    for (int j = threadIdx.x; j < 5184; j += 256) sl[j] = src[j];
    __syncthreads();
    int og = oc >> 4, fr = oc & 15;
    for (int t = threadIdx.x; t < 5184; t += 256) {
        int tap = t >> 6, i = t & 63;
        int ic = ic0 + i;
        int ks = ic >> 5, kch = (ic >> 3) & 3, icl = ic & 7;
        int lane = kch * 16 + fr;
        w6[(((size_t)(tap * 8 + ks) * 16 + og) * 64 + lane) * 8 + icl] =
            (_Float16)sl[i * 81 + tap];
    }
}

// conv1_w [oc][81] -> wT1 [t][oc]
__global__ void k_transpose_w1(const float* __restrict__ w, float* __restrict__ wT) {
    int t = blockIdx.x, oc = threadIdx.x;
    wT[t * 256 + oc] = w[oc * 81 + t];
}

// ---------------- conv1 + relu -> h3[ks][y][x][p][b][8] f16 ----------------
__global__ __launch_bounds__(256) void k_conv1(const float* __restrict__ x,
                                               const float* __restrict__ wT1,
                                               const float* __restrict__ bias,
                                               _Float16* __restrict__ h3) {
    __shared__ _Float16 hs[2][20][256];  // 20KB
    int b  = blockIdx.y;    // 256
    int rp = blockIdx.x;    // 10 row-pairs
    int oc = threadIdx.x;   // 256
    int oy0 = rp * 2;
    const float* xb = x + (size_t)b * 784;
    float bv = bias[oc];
    float acc0[20], acc1[20];
#pragma unroll
    for (int i = 0; i < 20; ++i) { acc0[i] = bv; acc1[i] = bv; }
    for (int ky = 0; ky < 9; ++ky) {
        const float* r0 = xb + (oy0 + ky) * 28;
        const float* r1 = r0 + 28;
        float x0[28], x1[28];
#pragma unroll
        for (int c = 0; c < 28; ++c) { x0[c] = r0[c]; x1[c] = r1[c]; }
#pragma unroll
        for (int kx = 0; kx < 9; ++kx) {
            float w = wT1[(ky * 9 + kx) * 256 + oc];
#pragma unroll
            for (int px = 0; px < 20; ++px) {
                acc0[px] += x0[px + kx] * w;
                acc1[px] += x1[px + kx] * w;
            }
        }
    }
#pragma unroll
    for (int px = 0; px < 20; ++px) {
        hs[0][px][oc] = (_Float16)fmaxf(acc0[px], 0.f);
        hs[1][px][oc] = (_Float16)fmaxf(acc1[px], 0.f);
    }
    __syncthreads();
    for (int cid = threadIdx.x; cid < 1280; cid += 256) {
        int kp = cid & 31;          // ks*4 + p
        int pos = cid >> 5;         // ry*20 + px
        int ry = pos / 20, px2 = pos % 20;
        int ks = kp >> 2, p = kp & 3;
        f16x8 val = *(const f16x8*)&hs[ry][px2][ks * 32 + p * 8];
        _Float16* dst = h3 + ((size_t)((ks * 400 + (oy0 + ry) * 20 + px2) * 4 + p) * 256 + b) * 8;
        *(f16x8*)dst = val;
    }
}

// ---------------- primary caps conv: 4-buffer distance-2 counted-vmcnt pipeline ----------------
// grid 1152 flat; block 256 = 4 waves (2x2), block tile 128(m) x 128(n), K=81 taps x 32 ic.
// ks = blk&7 -> XCD-affinity on split-K axis (round-robin %8): per-XCD L2 set = one slice.
// Staging layout identical to the verified 2-phase version (round 3, passed).
// Schedule upgrade (T3+T4): 4 LDS buffers, distance-2 prefetch, ONE raw s_barrier per
// tap, s_waitcnt vmcnt(8) in steady state (taps t+1,t+2 = 8 loads stay in flight across
// the barrier; never drains to 0 in-loop). Per-wave slack between issuing tap t's loads
// and consuming them = 2 full taps (~600cy) >= loaded-L2 latency -> MFMA pipe stays fed.
// Hazard proof (1 barrier/tap, 4 buffers): STAGE at tap t writes buf (t+2)&3, whose last
// reader was COMPUTE(t-2); every wave reaches barrier(t-1) only after its COMPUTE(t-2),
// and STAGE(t) executes only after passing barrier(t-1) -> write ordered after all reads.
__global__ __launch_bounds__(256, 2) void k_conv2_direct(
    const _Float16* __restrict__ h3, const _Float16* __restrict__ w6,
    float* __restrict__ pp) {
    __shared__ _Float16 Asl[4 * 4096];  // 32KB
    __shared__ _Float16 Bsl[4 * 4096];  // 32KB

    const int blk = blockIdx.x;
    const int ks = blk & 7;          // XCD = ks (round-robin %8)
    const int rest = blk >> 3;       // 0..143
    const int mt = rest % 72;
    const int nt = rest / 72;
    const int pos = mt >> 1, bhalf = mt & 1;
    const int py = pos / 6, px = pos % 6;
    const int tid = threadIdx.x;
    const int l = tid & 63;
    const int w = tid >> 6;
    const int wu = __builtin_amdgcn_readfirstlane(w);
    const int wm = w >> 1, wn = w & 1;
    const int p = l >> 4, fr = l & 15;

    // staging source pointers (per-lane), layout verified correct in round 3:
    //   A: h3[ks][win][p = tid>>7 (+2 on 2nd gll)][b = bhalf*128 + (tid&127)][icl]
    //   B: w6[(tap*8+ks)*8192 + nt*4096 + tid*8 (+2048 on 2nd gll)]
    const _Float16* aglb = h3 + (size_t)ks * 3276800 + (tid >> 7) * 2048 +
                           (bhalf * 128 + (tid & 127)) * 8;   // + win*8192
    const _Float16* bglb = w6 + (size_t)ks * 8192 + nt * 4096 + tid * 8;  // + tap*65536

#define STAGE(buf, aoff, boff)                                                     \
    do {                                                                           \
        const _Float16* _ga = aglb + (aoff);                                       \
        const _Float16* _gb = bglb + (boff);                                       \
        _Float16* _la = Asl + (buf) * 4096 + wu * 512;                             \
        _Float16* _lb = Bsl + (buf) * 4096 + wu * 512;                             \
        __builtin_amdgcn_global_load_lds(                                          \
            (const __attribute__((address_space(1))) void*)_ga,                    \
            (__attribute__((address_space(3))) void*)_la, 16, 0, 0);               \
        __builtin_amdgcn_global_load_lds(                                          \
            (const __attribute__((address_space(1))) void*)(_ga + 4096),           \
            (__attribute__((address_space(3))) void*)(_la + 2048), 16, 0, 0);      \
        __builtin_amdgcn_global_load_lds(                                          \
            (const __attribute__((address_space(1))) void*)_gb,                    \
            (__attribute__((address_space(3))) void*)(_lb), 16, 0, 0);             \
        __builtin_amdgcn_global_load_lds(                                          \
            (const __attribute__((address_space(1))) void*)(_gb + 2048),           \
            (__attribute__((address_space(3))) void*)(_lb + 2048), 16, 0, 0);      \
    } while (0)

    f32x4 acc[4][4];
    const f32x4 z = {0.f, 0.f, 0.f, 0.f};
#pragma unroll
    for (int mi = 0; mi < 4; ++mi)
#pragma unroll
        for (int ni = 0; ni < 4; ++ni) acc[mi][ni] = z;

#define COMPUTE(buf)                                                               \
    do {                                                                           \
        f16x8 af[4], bf[4];                                                        \
        const _Float16* _ab = Asl + (buf) * 4096 + p * 1024 + (wm * 64 + fr) * 8;  \
        const _Float16* _bb = Bsl + (buf) * 4096 + wn * 2048 + l * 8;              \
        _Pragma("unroll") for (int mi = 0; mi < 4; ++mi)                           \
            af[mi] = *(const f16x8*)(_ab + mi * 128);                              \
        _Pragma("unroll") for (int ni = 0; ni < 4; ++ni)                           \
            bf[ni] = *(const f16x8*)(_bb + ni * 512);                              \
        __builtin_amdgcn_s_setprio(1);                                             \
        _Pragma("unroll") for (int mi = 0; mi < 4; ++mi)                           \
            _Pragma("unroll") for (int ni = 0; ni < 4; ++ni)                       \
                acc[mi][ni] = __builtin_amdgcn_mfma_f32_16x16x32_f16(              \
                    af[mi], bf[ni], acc[mi][ni], 0, 0, 0);                         \
        __builtin_amdgcn_s_setprio(0);                                             \
    } while (0)

// barrier + make tap data visible: own loads drained to N, then block-wide rendezvous.
// sched_barrier(0) prevents the compiler from hoisting the ds_reads above the barrier.
#define SYNC(N)                                                                    \
    do {                                                                           \
        asm volatile("s_waitcnt vmcnt(" #N ")" ::: "memory");                      \
        __builtin_amdgcn_s_barrier();                                              \
        __builtin_amdgcn_sched_barrier(0);                                         \
    } while (0)

    // taps walk the 9x9 window row-major; win = plane offset of tap's window
    int win2 = (2 * py) * 20 + 2 * px;   // tap 0
    STAGE(0, (size_t)win2 * 8192, 0);
    int wx2 = 1; win2 += 1;              // tap 1
    STAGE(1, (size_t)win2 * 8192, 65536);
    size_t boff = 65536;
    for (int t = 0; t < 79; ++t) {
        // advance window to tap t+2 and prefetch it (distance 2)
        if (wx2 == 8) { wx2 = 0; win2 += 12; } else { ++wx2; win2 += 1; }
        boff += 65536;
        STAGE((t + 2) & 3, (size_t)win2 * 8192, boff);
        SYNC(8);                 // tap t's 4 loads landed; t+1,t+2 (8) stay in flight
        COMPUTE(t & 3);
    }
    SYNC(4);                     // tap 79 ready; tap 80's 4 still in flight
    COMPUTE(79 & 3);
    SYNC(0);                     // tap 80 ready
    COMPUTE(80 & 3);
#undef STAGE
#undef COMPUTE
#undef SYNC

    // epilogue: D[m][n], m=(lane>>4)*4+reg, n=lane&15; atomic split-K reduce
    const int row0 = (l >> 4) * 4;
    const int ncol = l & 15;
#pragma unroll
    for (int mi = 0; mi < 4; ++mi)
#pragma unroll
        for (int ni = 0; ni < 4; ++ni) {
            int n = nt * 128 + wn * 64 + ni * 16 + ncol;
#pragma unroll
            for (int reg = 0; reg < 4; ++reg) {
                int m = pos * 256 + bhalf * 128 + wm * 64 + mi * 16 + row0 + reg;
                atomAddF(&pp[(size_t)m * 256 + n], acc[mi][ni][reg]);
            }
        }
}

// ---------------- bias + primary squash -> u[i][b][d]  (pp m-order = pos*256+b) ----------------
__global__ __launch_bounds__(256) void k_sum_squash2(const float* __restrict__ pp,
                                                     const float* __restrict__ bias,
                                                     float* __restrict__ u) {
    int m = blockIdx.x * 8 + (threadIdx.x >> 5);
    int cap = threadIdx.x & 31;
    const float* p0 = pp + (size_t)m * 256 + cap * 8;
    float s[8], sq = 0.f;
#pragma unroll
    for (int d = 0; d < 8; ++d) {
        float a = p0[d] + bias[cap * 8 + d];
        sq += a * a; s[d] = a;
    }
    float scale = sq / ((1.0f + sq) * sqrtf(sq + 1e-8f));
    int pos = m >> 8, b = m & 255;
    int i = cap * 36 + pos;
    float* up = u + ((size_t)i * 256 + b) * 8;
    ((float4*)up)[0] = make_float4(scale * s[0], scale * s[1], scale * s[2], scale * s[3]);
    ((float4*)up)[1] = make_float4(scale * s[4], scale * s[5], scale * s[6], scale * s[7]);
}

// ---------------- build u_hat (bf16) [i][j][b][o] ----------------
__global__ __launch_bounds__(256) void k_build_uhat(const float* __restrict__ u,
                                                    const float* __restrict__ W,
                                                    unsigned short* __restrict__ UH) {
    __shared__ float Ws[1280];
    int i = blockIdx.x;  // 1152
    for (int t = threadIdx.x; t < 1280; t += 256) Ws[t] = W[(size_t)i * 1280 + t];
    __syncthreads();
    int b = threadIdx.x;  // 256
    const float* uptr = u + ((size_t)i * 256 + b) * 8;
    float u8[8];
    ((float4*)u8)[0] = ((const float4*)uptr)[0];
    ((float4*)u8)[1] = ((const float4*)uptr)[1];
#pragma unroll
    for (int j = 0; j < 10; ++j) {
        float o16[16];
#pragma unroll
        for (int o = 0; o < 16; ++o) o16[o] = 0.f;
#pragma unroll
        for (int d = 0; d < 8; ++d) {
            const float* wp = Ws + d * 160 + j * 16;
#pragma unroll
            for (int o = 0; o < 16; ++o) o16[o] += u8[d] * wp[o];
        }
        u16x8 h0, h1;
#pragma unroll
        for (int o = 0; o < 8; ++o) { h0[o] = f2bf(o16[o]); h1[o] = f2bf(o16[8 + o]); }
        unsigned short* dst = UH + ((size_t)(i * 10 + j) * 256 + b) * 16;
        *(u16x8*)dst = h0;
        *(u16x8*)(dst + 8) = h1;
    }
}

// ---------------- routing iter 0: s0 = 0.1 * sum_i u_hat ----------------
__global__ __launch_bounds__(256) void k_route_s0(const unsigned short* __restrict__ UH,
                                                  float* __restrict__ SP) {
    int it = blockIdx.x, bt = blockIdx.y;
    int b0 = bt * 64, i0 = it * 8;
    int b_l = threadIdx.x & 63;
    int og = __builtin_amdgcn_readfirstlane((int)(threadIdx.x >> 6));
    float acc[10][4];
#pragma unroll
    for (int j = 0; j < 10; ++j)
#pragma unroll
        for (int o = 0; o < 4; ++o) acc[j][o] = 0.f;
    for (int li = 0; li < 8; ++li) {
        const unsigned short* up = UH + ((size_t)(i0 + li) * 10 * 256 + b0 + b_l) * 16 + og * 4;
#pragma unroll
        for (int j = 0; j < 10; ++j) {
            u16x4 t = *(const u16x4*)(up + j * 4096);
#pragma unroll
            for (int o = 0; o < 4; ++o) acc[j][o] += bf2f(t[o]);
        }
    }
    float* sp = SP + ((size_t)it * 256 + b0 + b_l) * 160 + og * 4;
#pragma unroll
    for (int j = 0; j < 10; ++j)
        *(float4*)(sp + j * 16) = make_float4(0.1f * acc[j][0], 0.1f * acc[j][1],
                                              0.1f * acc[j][2], 0.1f * acc[j][3]);
}

// ---------------- fused routing: logits (+)= <u_hat,v>; softmax; s-partials ----------------
// grid (144,4); block 256. add=0: L := agreement (prior logits zero). storeL: write L back.
__global__ __launch_bounds__(256) void k_route_as(float* __restrict__ L,
                                                  const unsigned short* __restrict__ UH,
                                                  const float* __restrict__ V,
                                                  float* __restrict__ SP,
                                                  int add, int storeL) {
    __shared__ float VL[64][165];
    __shared__ float LG[64][81];
    int it = blockIdx.x, bt = blockIdx.y;
    int b0 = bt * 64, i0 = it * 8;
    int b_l = threadIdx.x & 63;
    int ig = __builtin_amdgcn_readfirstlane((int)(threadIdx.x >> 6));
    int b_r = threadIdx.x >> 2, part = threadIdx.x & 3;
    {
        const float4* vsrc = (const float4*)(V + (size_t)(b0 + b_r) * 160 + part * 40);
#pragma unroll
        for (int q = 0; q < 10; ++q) {
            float4 vv = vsrc[q]; int c = part * 40 + q * 4;
            VL[b_r][c] = vv.x; VL[b_r][c + 1] = vv.y; VL[b_r][c + 2] = vv.z; VL[b_r][c + 3] = vv.w;
        }
        if (add) {
            const float4* lsrc = (const float4*)(L + (size_t)(b0 + b_r) * 11520 + i0 * 10 + part * 20);
#pragma unroll
            for (int q = 0; q < 5; ++q) {
                float4 t = lsrc[q]; int c = part * 20 + q * 4;
                LG[b_r][c] = t.x; LG[b_r][c + 1] = t.y; LG[b_r][c + 2] = t.z; LG[b_r][c + 3] = t.w;
            }
        }
    }
    __syncthreads();
    // agreement phase: thread group ig handles 2 i's
#pragma unroll
    for (int ii = 0; ii < 2; ++ii) {
        int il = ig * 2 + ii;
        int i = i0 + il;
        const unsigned short* up = UH + ((size_t)i * 10 * 256 + b0 + b_l) * 16;
#pragma unroll
        for (int j = 0; j < 10; ++j) {
            u16x8 ua = *(const u16x8*)(up + j * 4096);
            u16x8 ub = *(const u16x8*)(up + j * 4096 + 8);
            float a = 0.f;
#pragma unroll
            for (int o = 0; o < 8; ++o) a += bf2f(ua[o]) * VL[b_l][j * 16 + o];
#pragma unroll
            for (int o = 0; o < 8; ++o) a += bf2f(ub[o]) * VL[b_l][j * 16 + 8 + o];
            float base = add ? LG[b_l][il * 10 + j] : 0.f;
            LG[b_l][il * 10 + j] = base + a;
        }
    }
    __syncthreads();
    if (storeL) {
        float4* ldst = (float4*)(L + (size_t)(b0 + b_r) * 11520 + i0 * 10 + part * 20);
#pragma unroll
        for (int q = 0; q < 5; ++q) {
            int c = part * 20 + q * 4;
            ldst[q] = make_float4(LG[b_r][c], LG[b_r][c + 1], LG[b_r][c + 2], LG[b_r][c + 3]);
        }
    }
    // s phase: softmax of fresh logits, accumulate c * u_hat (og = ig reuse)
    float acc[10][4];
#pragma unroll
    for (int j = 0; j < 10; ++j)
#pragma unroll
        for (int o = 0; o < 4; ++o) acc[j][o] = 0.f;
    for (int li = 0; li < 8; ++li) {
        float lg[10];
#pragma unroll
        for (int j = 0; j < 10; ++j) lg[j] = LG[b_l][li * 10 + j];
        float m = lg[0];
#pragma unroll
        for (int j = 1; j < 10; ++j) m = fmaxf(m, lg[j]);
        float e[10], ssum = 0.f;
#pragma unroll
        for (int j = 0; j < 10; ++j) { e[j] = __expf(lg[j] - m); ssum += e[j]; }
        float inv = 1.0f / ssum;
        const unsigned short* up = UH + ((size_t)(i0 + li) * 10 * 256 + b0 + b_l) * 16 + ig * 4;
#pragma unroll
        for (int j = 0; j < 10; ++j) {
            float cj = e[j] * inv;
            u16x4 t = *(const u16x4*)(up + j * 4096);
#pragma unroll
            for (int o = 0; o < 4; ++o) acc[j][o] += cj * bf2f(t[o]);
        }
    }
    float* sp = SP + ((size_t)it * 256 + b0 + b_l) * 160 + ig * 4;
#pragma unroll
    for (int j = 0; j < 10; ++j)
        *(float4*)(sp + j * 16) = make_float4(acc[j][0], acc[j][1], acc[j][2], acc[j][3]);
}

// ---------------- routing: reduce partials + squash -> v ----------------
__global__ __launch_bounds__(256) void k_route_v(const float* __restrict__ SP,
                                                 float* __restrict__ vout) {
    int n = blockIdx.x * 256 + threadIdx.x;  // 40960
    float ssum = 0.f;
    for (int t = 0; t < 144; ++t) ssum += SP[(size_t)t * 40960 + n];
    float sq = ssum * ssum;
    float tot = sq;
#pragma unroll
    for (int mask = 1; mask < 16; mask <<= 1) tot += __shfl_xor(tot, mask, 64);
    float scale = tot / ((1.0f + tot) * sqrtf(tot + 1e-8f));
    vout[n] = scale * ssum;
}

// ---------------- launcher ----------------
extern "C" void kernel_launch(void* const* d_in, const int* in_sizes, int n_in,
                              void* d_out, int out_size, void* d_ws, size_t ws_size,
                              hipStream_t stream) {
    (void)in_sizes; (void)n_in; (void)out_size; (void)ws_size;
    const float* x   = (const float*)d_in[0];
    const float* c1w = (const float*)d_in[1];
    const float* c1b = (const float*)d_in[2];
    const float* pcw = (const float*)d_in[3];
    const float* pcb = (const float*)d_in[4];
    const float* Wd  = (const float*)d_in[5];
    float* out = (float*)d_out;
    char* wsb  = (char*)d_ws;

    unsigned short* uh = (unsigned short*)(wsb + UHAT_OFF);
    _Float16* w6 = (_Float16*)(wsb + W6_OFF);
    _Float16* h3 = (_Float16*)(wsb + H3_OFF);
    float* wT1 = (float*)(wsb + WT1_OFF);
    float* pp  = (float*)(wsb + PP_OFF);
    float* u   = (float*)(wsb + U_OFF);
    float* sp  = (float*)(wsb + SP_OFF);
    float* lg  = (float*)(wsb + L_OFF);
    float* v   = (float*)(wsb + V_OFF);

    hipMemsetAsync(pp, 0, (size_t)9216 * 256 * sizeof(float), stream);

    k_prep_w<<<dim3(256, 4), 256, 0, stream>>>(pcw, w6);
    k_transpose_w1<<<81, 256, 0, stream>>>(c1w, wT1);
    k_conv1<<<dim3(10, 256), 256, 0, stream>>>(x, wT1, c1b, h3);
    k_conv2_direct<<<dim3(1152), 256, 0, stream>>>(h3, w6, pp);
    k_sum_squash2<<<1152, 256, 0, stream>>>(pp, pcb, u);
    k_build_uhat<<<1152, 256, 0, stream>>>(u, Wd, uh);

    // iter 0: c = 0.1 exactly
    k_route_s0<<<dim3(144, 4), 256, 0, stream>>>(uh, sp);
    k_route_v<<<160, 256, 0, stream>>>(sp, v);
    // iter 1 (fused agree+softmax+s); logits were zero -> add=0, store for iter 2
    k_route_as<<<dim3(144, 4), 256, 0, stream>>>(lg, uh, v, sp, 0, 1);
    k_route_v<<<160, 256, 0, stream>>>(sp, v);
    // iter 2 (fused); last use of logits -> no store
    k_route_as<<<dim3(144, 4), 256, 0, stream>>>(lg, uh, v, sp, 1, 0);
    k_route_v<<<160, 256, 0, stream>>>(sp, out);
}

// Round 5
// 474.286 us; speedup vs baseline: 1.0188x; 1.0006x over previous
//
#include <hip/hip_runtime.h>
#include <hip/hip_bf16.h>

// ---------------- problem constants ----------------
#define NI 1152
// conv2 GEMM view: M=9216 as (pos,b)=36*256; N=256 (oc); K=81 taps x 256 ic

typedef __attribute__((ext_vector_type(8))) _Float16 f16x8;
typedef __attribute__((ext_vector_type(4))) float f32x4;
typedef __attribute__((ext_vector_type(8))) unsigned short u16x8;
typedef __attribute__((ext_vector_type(4))) unsigned short u16x4;

// ws layout (bytes). Phase-1 buffers (w6,h3,wT1,pp) alias under uhat (94.4MB):
static const size_t UHAT_OFF = 0;                        // bf16 1152*10*256*16 = 94,371,840
static const size_t W6_OFF   = 0;                        // f16 81*8*16*64*8 = 10,616,832 B
static const size_t H3_OFF   = 10747904UL;               // f16 8*400*4*256*8 = 52,428,800 B
static const size_t WT1_OFF  = 63176704UL;               // f32 81*256
static const size_t PP_OFF   = 63259648UL;               // f32 9216*256 (ends 72.7MB < 94.4MB)
static const size_t U_OFF    = 94371840UL;               // f32 u[i][b][d]
static const size_t SP_OFF   = 103809024UL;              // f32 144*256*160
static const size_t L_OFF    = 127401984UL;               // f32 256*1152*10
static const size_t V_OFF    = 139198464UL;               // f32 256*160

__device__ __forceinline__ unsigned short f2bf(float x) {
    unsigned u = __builtin_bit_cast(unsigned, x);
    u += 0x7fffu + ((u >> 16) & 1u);
    return (unsigned short)(u >> 16);
}
__device__ __forceinline__ float bf2f(unsigned short h) {
    return __builtin_bit_cast(float, (unsigned)h << 16);
}
__device__ __forceinline__ void atomAddF(float* p, float v) {
    __hip_atomic_fetch_add(p, v, __ATOMIC_RELAXED, __HIP_MEMORY_SCOPE_AGENT);
}

// ---------------- weight prep: pc_w [oc][ic*81+tap] -> w6 frag-linear ----------------
// w6 linear: (((tap*8+ks)*16 + og)*64 + lane)*8 + icl
//   og=oc>>4, fr=oc&15, lane=kch*16+fr, ic=ks*32+kch*8+icl
__global__ __launch_bounds__(256) void k_prep_w(const float* __restrict__ pcw,
                                                _Float16* __restrict__ w6) {
    __shared__ float sl[5184];
    int oc  = blockIdx.x;       // 256
    int ic0 = blockIdx.y * 64;  // 4 chunks
    const float* src = pcw + (size_t)oc * 20736 + (size_t)ic0 * 81;
    for (int j = threadIdx.x; j < 5184; j += 256) sl[j] = src[j];
    __syncthreads();
    int og = oc >> 4, fr = oc & 15;
    for (int t = threadIdx.x; t < 5184; t += 256) {
        int tap = t >> 6, i = t & 63;
        int ic = ic0 + i;
        int ks = ic >> 5, kch = (ic >> 3) & 3, icl = ic & 7;
        int lane = kch * 16 + fr;
        w6[(((size_t)(tap * 8 + ks) * 16 + og) * 64 + lane) * 8 + icl] =
            (_Float16)sl[i * 81 + tap];
    }
}

// conv1_w [oc][81] -> wT1 [t][oc]
__global__ void k_transpose_w1(const float* __restrict__ w, float* __restrict__ wT) {
    int t = blockIdx.x, oc = threadIdx.x;
    wT[t * 256 + oc] = w[oc * 81 + t];
}

// ---------------- conv1 + relu -> h3[ks][y][x][p][b][8] f16 ----------------
__global__ __launch_bounds__(256) void k_conv1(const float* __restrict__ x,
                                               const float* __restrict__ wT1,
                                               const float* __restrict__ bias,
                                               _Float16* __restrict__ h3) {
    __shared__ _Float16 hs[2][20][256];  // 20KB
    int b  = blockIdx.y;    // 256
    int rp = blockIdx.x;    // 10 row-pairs
    int oc = threadIdx.x;   // 256
    int oy0 = rp * 2;
    const float* xb = x + (size_t)b * 784;
    float bv = bias[oc];
    float acc0[20], acc1[20];
#pragma unroll
    for (int i = 0; i < 20; ++i) { acc0[i] = bv; acc1[i] = bv; }
    for (int ky = 0; ky < 9; ++ky) {
        const float* r0 = xb + (oy0 + ky) * 28;
        const float* r1 = r0 + 28;
        float x0[28], x1[28];
#pragma unroll
        for (int c = 0; c < 28; ++c) { x0[c] = r0[c]; x1[c] = r1[c]; }
#pragma unroll
        for (int kx = 0; kx < 9; ++kx) {
            float w = wT1[(ky * 9 + kx) * 256 + oc];
#pragma unroll
            for (int px = 0; px < 20; ++px) {
                acc0[px] += x0[px + kx] * w;
                acc1[px] += x1[px + kx] * w;
            }
        }
    }
#pragma unroll
    for (int px = 0; px < 20; ++px) {
        hs[0][px][oc] = (_Float16)fmaxf(acc0[px], 0.f);
        hs[1][px][oc] = (_Float16)fmaxf(acc1[px], 0.f);
    }
    __syncthreads();
    for (int cid = threadIdx.x; cid < 1280; cid += 256) {
        int kp = cid & 31;          // ks*4 + p
        int pos = cid >> 5;         // ry*20 + px
        int ry = pos / 20, px2 = pos % 20;
        int ks = kp >> 2, p = kp & 3;
        f16x8 val = *(const f16x8*)&hs[ry][px2][ks * 32 + p * 8];
        _Float16* dst = h3 + ((size_t)((ks * 400 + (oy0 + ry) * 20 + px2) * 4 + p) * 256 + b) * 8;
        *(f16x8*)dst = val;
    }
}

// ---------------- primary caps conv: fat-phase (2-tap, BK=64) LDS double-buffer ----------------
// grid 1152 flat; block 256 = 4 waves (2x2), block tile 128(m) x 128(n).
// ks = blk&7 -> XCD-affinity on split-K axis (round-robin %8).
// Phase = GRANULE of 2 taps (BK=64): stage 32KB (A 16 + B 16) once per phase via
// global_load_lds(16B); compute 32 MFMA per wave per phase with all 16 frags loaded
// up-front (compiler pipelines fine-grained lgkm waits across the whole cluster).
// Halves the per-phase costs (barrier rendezvous, wait ramp, dep-chain restart) that
// round-3/4 profiling showed dominate at BK=32 (MfmaUtil stuck ~24% across schedules).
// Ordering per phase (round-3-proven): STAGE(next granule) -> COMPUTE(cur) ->
// __syncthreads (drains stage loads issued a full ~1200cy compute earlier = cheap).
// Hazards: STAGE(g+1) overwrites granule g-1's buffer, last read in phase g-1 and
// protected by that phase's barrier; COMPUTE(g) reads data drained at barrier g-1.
__global__ __launch_bounds__(256, 2) void k_conv2_direct(
    const _Float16* __restrict__ h3, const _Float16* __restrict__ w6,
    float* __restrict__ pp) {
    __shared__ _Float16 Asl[2 * 8192];  // 2 granules x (2 taps x 4096 f16) = 32KB
    __shared__ _Float16 Bsl[2 * 8192];  // 32KB

    const int blk = blockIdx.x;
    const int ks = blk & 7;          // XCD = ks (round-robin %8)
    const int rest = blk >> 3;       // 0..143
    const int mt = rest % 72;
    const int nt = rest / 72;
    const int pos = mt >> 1, bhalf = mt & 1;
    const int py = pos / 6, px = pos % 6;
    const int tid = threadIdx.x;
    const int l = tid & 63;
    const int w = tid >> 6;
    const int wu = __builtin_amdgcn_readfirstlane(w);
    const int wm = w >> 1, wn = w & 1;
    const int p = l >> 4, fr = l & 15;

    // staging source pointers (per-lane), layout verified (rounds 3-4 passed):
    //   A: h3[ks][win][p = tid>>7 (+2 on 2nd gll)][b = bhalf*128 + (tid&127)][icl]
    //   B: w6[(tap*8+ks)*8192 + nt*4096 + tid*8 (+2048 on 2nd gll)]
    const _Float16* aglb = h3 + (size_t)ks * 3276800 + (tid >> 7) * 2048 +
                           (bhalf * 128 + (tid & 127)) * 8;   // + win*8192
    const _Float16* bglb = w6 + (size_t)ks * 8192 + nt * 4096 + tid * 8;  // + tap*65536

// stage ONE tap into granule-buffer `buf`, tap-slot `slot` (0/1)
#define STAGE_TAP(buf, slot, winv, boffv)                                          \
    do {                                                                           \
        const _Float16* _ga = aglb + (size_t)(winv) * 8192;                        \
        const _Float16* _gb = bglb + (boffv);                                      \
        _Float16* _la = Asl + (buf) * 8192 + (slot) * 4096 + wu * 512;             \
        _Float16* _lb = Bsl + (buf) * 8192 + (slot) * 4096 + wu * 512;             \
        __builtin_amdgcn_global_load_lds(                                          \
            (const __attribute__((address_space(1))) void*)_ga,                    \
            (__attribute__((address_space(3))) void*)_la, 16, 0, 0);               \
        __builtin_amdgcn_global_load_lds(                                          \
            (const __attribute__((address_space(1))) void*)(_ga + 4096),           \
            (__attribute__((address_space(3))) void*)(_la + 2048), 16, 0, 0);      \
        __builtin_amdgcn_global_load_lds(                                          \
            (const __attribute__((address_space(1))) void*)_gb,                    \
            (__attribute__((address_space(3))) void*)(_lb), 16, 0, 0);             \
        __builtin_amdgcn_global_load_lds(                                          \
            (const __attribute__((address_space(1))) void*)(_gb + 2048),           \
            (__attribute__((address_space(3))) void*)(_lb + 2048), 16, 0, 0);      \
    } while (0)

// advance tap tracker (row-major 9x9 window walk) + B offset
#define ADV()                                                                      \
    do {                                                                           \
        if (wx2 == 8) { wx2 = 0; win2 += 12; } else { ++wx2; win2 += 1; }          \
        boff += 65536;                                                             \
    } while (0)

    f32x4 acc[4][4];
    const f32x4 z = {0.f, 0.f, 0.f, 0.f};
#pragma unroll
    for (int mi = 0; mi < 4; ++mi)
#pragma unroll
        for (int ni = 0; ni < 4; ++ni) acc[mi][ni] = z;

// load all frags of both tap-slots, then one 32-MFMA cluster
#define COMPUTE2(buf)                                                              \
    do {                                                                           \
        f16x8 af[2][4], bf[2][4];                                                  \
        _Pragma("unroll") for (int s = 0; s < 2; ++s) {                            \
            const _Float16* _ab =                                                  \
                Asl + (buf) * 8192 + s * 4096 + p * 1024 + (wm * 64 + fr) * 8;     \
            const _Float16* _bb =                                                  \
                Bsl + (buf) * 8192 + s * 4096 + wn * 2048 + l * 8;                 \
            _Pragma("unroll") for (int mi = 0; mi < 4; ++mi)                       \
                af[s][mi] = *(const f16x8*)(_ab + mi * 128);                       \
            _Pragma("unroll") for (int ni = 0; ni < 4; ++ni)                       \
                bf[s][ni] = *(const f16x8*)(_bb + ni * 512);                       \
        }                                                                          \
        __builtin_amdgcn_s_setprio(1);                                             \
        _Pragma("unroll") for (int s = 0; s < 2; ++s)                              \
            _Pragma("unroll") for (int mi = 0; mi < 4; ++mi)                       \
                _Pragma("unroll") for (int ni = 0; ni < 4; ++ni)                   \
                    acc[mi][ni] = __builtin_amdgcn_mfma_f32_16x16x32_f16(          \
                        af[s][mi], bf[s][ni], acc[mi][ni], 0, 0, 0);               \
        __builtin_amdgcn_s_setprio(0);                                             \
    } while (0)

#define COMPUTE1(buf)                                                              \
    do {                                                                           \
        f16x8 af[4], bf[4];                                                        \
        const _Float16* _ab = Asl + (buf) * 8192 + p * 1024 + (wm * 64 + fr) * 8;  \
        const _Float16* _bb = Bsl + (buf) * 8192 + wn * 2048 + l * 8;              \
        _Pragma("unroll") for (int mi = 0; mi < 4; ++mi)                           \
            af[mi] = *(const f16x8*)(_ab + mi * 128);                              \
        _Pragma("unroll") for (int ni = 0; ni < 4; ++ni)                           \
            bf[ni] = *(const f16x8*)(_bb + ni * 512);                              \
        __builtin_amdgcn_s_setprio(1);                                             \
        _Pragma("unroll") for (int mi = 0; mi < 4; ++mi)                           \
            _Pragma("unroll") for (int ni = 0; ni < 4; ++ni)                       \
                acc[mi][ni] = __builtin_amdgcn_mfma_f32_16x16x32_f16(              \
                    af[mi], bf[ni], acc[mi][ni], 0, 0, 0);                         \
        __builtin_amdgcn_s_setprio(0);                                             \
    } while (0)

    // granules: g<40 = taps {2g, 2g+1}; granule 40 = tap 80 (slot 0)
    int win2 = (2 * py) * 20 + 2 * px;  // tap 0
    int wx2 = 0;
    size_t boff = 0;
    STAGE_TAP(0, 0, win2, boff);        // tap 0
    ADV();
    STAGE_TAP(0, 1, win2, boff);        // tap 1
    __syncthreads();                    // granule 0 ready
    int buf = 0;
    for (int g = 0; g < 40; ++g) {
        ADV();
        STAGE_TAP(buf ^ 1, 0, win2, boff);           // tap 2g+2
        if (g < 39) {
            ADV();
            STAGE_TAP(buf ^ 1, 1, win2, boff);       // tap 2g+3
        }
        COMPUTE2(buf);
        __syncthreads();               // drains prefetch (issued ~1200cy ago); swap safe
        buf ^= 1;
    }
    COMPUTE1(buf);                     // granule 40 = tap 80
#undef STAGE_TAP
#undef ADV
#undef COMPUTE2
#undef COMPUTE1

    // epilogue: D[m][n], m=(lane>>4)*4+reg, n=lane&15; atomic split-K reduce
    const int row0 = (l >> 4) * 4;
    const int ncol = l & 15;
#pragma unroll
    for (int mi = 0; mi < 4; ++mi)
#pragma unroll
        for (int ni = 0; ni < 4; ++ni) {
            int n = nt * 128 + wn * 64 + ni * 16 + ncol;
#pragma unroll
            for (int reg = 0; reg < 4; ++reg) {
                int m = pos * 256 + bhalf * 128 + wm * 64 + mi * 16 + row0 + reg;
                atomAddF(&pp[(size_t)m * 256 + n], acc[mi][ni][reg]);
            }
        }
}

// ---------------- bias + primary squash -> u[i][b][d]  (pp m-order = pos*256+b) ----------------
__global__ __launch_bounds__(256) void k_sum_squash2(const float* __restrict__ pp,
                                                     const float* __restrict__ bias,
                                                     float* __restrict__ u) {
    int m = blockIdx.x * 8 + (threadIdx.x >> 5);
    int cap = threadIdx.x & 31;
    const float* p0 = pp + (size_t)m * 256 + cap * 8;
    float s[8], sq = 0.f;
#pragma unroll
    for (int d = 0; d < 8; ++d) {
        float a = p0[d] + bias[cap * 8 + d];
        sq += a * a; s[d] = a;
    }
    float scale = sq / ((1.0f + sq) * sqrtf(sq + 1e-8f));
    int pos = m >> 8, b = m & 255;
    int i = cap * 36 + pos;
    float* up = u + ((size_t)i * 256 + b) * 8;
    ((float4*)up)[0] = make_float4(scale * s[0], scale * s[1], scale * s[2], scale * s[3]);
    ((float4*)up)[1] = make_float4(scale * s[4], scale * s[5], scale * s[6], scale * s[7]);
}

// ---------------- build u_hat (bf16) [i][j][b][o] ----------------
__global__ __launch_bounds__(256) void k_build_uhat(const float* __restrict__ u,
                                                    const float* __restrict__ W,
                                                    unsigned short* __restrict__ UH) {
    __shared__ float Ws[1280];
    int i = blockIdx.x;  // 1152
    for (int t = threadIdx.x; t < 1280; t += 256) Ws[t] = W[(size_t)i * 1280 + t];
    __syncthreads();
    int b = threadIdx.x;  // 256
    const float* uptr = u + ((size_t)i * 256 + b) * 8;
    float u8[8];
    ((float4*)u8)[0] = ((const float4*)uptr)[0];
    ((float4*)u8)[1] = ((const float4*)uptr)[1];
#pragma unroll
    for (int j = 0; j < 10; ++j) {
        float o16[16];
#pragma unroll
        for (int o = 0; o < 16; ++o) o16[o] = 0.f;
#pragma unroll
        for (int d = 0; d < 8; ++d) {
            const float* wp = Ws + d * 160 + j * 16;
#pragma unroll
            for (int o = 0; o < 16; ++o) o16[o] += u8[d] * wp[o];
        }
        u16x8 h0, h1;
#pragma unroll
        for (int o = 0; o < 8; ++o) { h0[o] = f2bf(o16[o]); h1[o] = f2bf(o16[8 + o]); }
        unsigned short* dst = UH + ((size_t)(i * 10 + j) * 256 + b) * 16;
        *(u16x8*)dst = h0;
        *(u16x8*)(dst + 8) = h1;
    }
}

// ---------------- routing iter 0: s0 = 0.1 * sum_i u_hat ----------------
__global__ __launch_bounds__(256) void k_route_s0(const unsigned short* __restrict__ UH,
                                                  float* __restrict__ SP) {
    int it = blockIdx.x, bt = blockIdx.y;
    int b0 = bt * 64, i0 = it * 8;
    int b_l = threadIdx.x & 63;
    int og = __builtin_amdgcn_readfirstlane((int)(threadIdx.x >> 6));
    float acc[10][4];
#pragma unroll
    for (int j = 0; j < 10; ++j)
#pragma unroll
        for (int o = 0; o < 4; ++o) acc[j][o] = 0.f;
    for (int li = 0; li < 8; ++li) {
        const unsigned short* up = UH + ((size_t)(i0 + li) * 10 * 256 + b0 + b_l) * 16 + og * 4;
#pragma unroll
        for (int j = 0; j < 10; ++j) {
            u16x4 t = *(const u16x4*)(up + j * 4096);
#pragma unroll
            for (int o = 0; o < 4; ++o) acc[j][o] += bf2f(t[o]);
        }
    }
    float* sp = SP + ((size_t)it * 256 + b0 + b_l) * 160 + og * 4;
#pragma unroll
    for (int j = 0; j < 10; ++j)
        *(float4*)(sp + j * 16) = make_float4(0.1f * acc[j][0], 0.1f * acc[j][1],
                                              0.1f * acc[j][2], 0.1f * acc[j][3]);
}

// ---------------- fused routing: logits (+)= <u_hat,v>; softmax; s-partials ----------------
// grid (144,4); block 256. add=0: L := agreement (prior logits zero). storeL: write L back.
__global__ __launch_bounds__(256) void k_route_as(float* __restrict__ L,
                                                  const unsigned short* __restrict__ UH,
                                                  const float* __restrict__ V,
                                                  float* __restrict__ SP,
                                                  int add, int storeL) {
    __shared__ float VL[64][165];
    __shared__ float LG[64][81];
    int it = blockIdx.x, bt = blockIdx.y;
    int b0 = bt * 64, i0 = it * 8;
    int b_l = threadIdx.x & 63;
    int ig = __builtin_amdgcn_readfirstlane((int)(threadIdx.x >> 6));
    int b_r = threadIdx.x >> 2, part = threadIdx.x & 3;
    {
        const float4* vsrc = (const float4*)(V + (size_t)(b0 + b_r) * 160 + part * 40);
#pragma unroll
        for (int q = 0; q < 10; ++q) {
            float4 vv = vsrc[q]; int c = part * 40 + q * 4;
            VL[b_r][c] = vv.x; VL[b_r][c + 1] = vv.y; VL[b_r][c + 2] = vv.z; VL[b_r][c + 3] = vv.w;
        }
        if (add) {
            const float4* lsrc = (const float4*)(L + (size_t)(b0 + b_r) * 11520 + i0 * 10 + part * 20);
#pragma unroll
            for (int q = 0; q < 5; ++q) {
                float4 t = lsrc[q]; int c = part * 20 + q * 4;
                LG[b_r][c] = t.x; LG[b_r][c + 1] = t.y; LG[b_r][c + 2] = t.z; LG[b_r][c + 3] = t.w;
            }
        }
    }
    __syncthreads();
    // agreement phase: thread group ig handles 2 i's
#pragma unroll
    for (int ii = 0; ii < 2; ++ii) {
        int il = ig * 2 + ii;
        int i = i0 + il;
        const unsigned short* up = UH + ((size_t)i * 10 * 256 + b0 + b_l) * 16;
#pragma unroll
        for (int j = 0; j < 10; ++j) {
            u16x8 ua = *(const u16x8*)(up + j * 4096);
            u16x8 ub = *(const u16x8*)(up + j * 4096 + 8);
            float a = 0.f;
#pragma unroll
            for (int o = 0; o < 8; ++o) a += bf2f(ua[o]) * VL[b_l][j * 16 + o];
#pragma unroll
            for (int o = 0; o < 8; ++o) a += bf2f(ub[o]) * VL[b_l][j * 16 + 8 + o];
            float base = add ? LG[b_l][il * 10 + j] : 0.f;
            LG[b_l][il * 10 + j] = base + a;
        }
    }
    __syncthreads();
    if (storeL) {
        float4* ldst = (float4*)(L + (size_t)(b0 + b_r) * 11520 + i0 * 10 + part * 20);
#pragma unroll
        for (int q = 0; q < 5; ++q) {
            int c = part * 20 + q * 4;
            ldst[q] = make_float4(LG[b_r][c], LG[b_r][c + 1], LG[b_r][c + 2], LG[b_r][c + 3]);
        }
    }
    // s phase: softmax of fresh logits, accumulate c * u_hat (og = ig reuse)
    float acc[10][4];
#pragma unroll
    for (int j = 0; j < 10; ++j)
#pragma unroll
        for (int o = 0; o < 4; ++o) acc[j][o] = 0.f;
    for (int li = 0; li < 8; ++li) {
        float lg[10];
#pragma unroll
        for (int j = 0; j < 10; ++j) lg[j] = LG[b_l][li * 10 + j];
        float m = lg[0];
#pragma unroll
        for (int j = 1; j < 10; ++j) m = fmaxf(m, lg[j]);
        float e[10], ssum = 0.f;
#pragma unroll
        for (int j = 0; j < 10; ++j) { e[j] = __expf(lg[j] - m); ssum += e[j]; }
        float inv = 1.0f / ssum;
        const unsigned short* up = UH + ((size_t)(i0 + li) * 10 * 256 + b0 + b_l) * 16 + ig * 4;
#pragma unroll
        for (int j = 0; j < 10; ++j) {
            float cj = e[j] * inv;
            u16x4 t = *(const u16x4*)(up + j * 4096);
#pragma unroll
            for (int o = 0; o < 4; ++o) acc[j][o] += cj * bf2f(t[o]);
        }
    }
    float* sp = SP + ((size_t)it * 256 + b0 + b_l) * 160 + ig * 4;
#pragma unroll
    for (int j = 0; j < 10; ++j)
        *(float4*)(sp + j * 16) = make_float4(acc[j][0], acc[j][1], acc[j][2], acc[j][3]);
}

// ---------------- routing: reduce partials + squash -> v ----------------
__global__ __launch_bounds__(256) void k_route_v(const float* __restrict__ SP,
                                                 float* __restrict__ vout) {
    int n = blockIdx.x * 256 + threadIdx.x;  // 40960
    float ssum = 0.f;
    for (int t = 0; t < 144; ++t) ssum += SP[(size_t)t * 40960 + n];
    float sq = ssum * ssum;
    float tot = sq;
#pragma unroll
    for (int mask = 1; mask < 16; mask <<= 1) tot += __shfl_xor(tot, mask, 64);
    float scale = tot / ((1.0f + tot) * sqrtf(tot + 1e-8f));
    vout[n] = scale * ssum;
}

// ---------------- launcher ----------------
extern "C" void kernel_launch(void* const* d_in, const int* in_sizes, int n_in,
                              void* d_out, int out_size, void* d_ws, size_t ws_size,
                              hipStream_t stream) {
    (void)in_sizes; (void)n_in; (void)out_size; (void)ws_size;
    const float* x   = (const float*)d_in[0];
    const float* c1w = (const float*)d_in[1];
    const float* c1b = (const float*)d_in[2];
    const float* pcw = (const float*)d_in[3];
    const float* pcb = (const float*)d_in[4];
    const float* Wd  = (const float*)d_in[5];
    float* out = (float*)d_out;
    char* wsb  = (char*)d_ws;

    unsigned short* uh = (unsigned short*)(wsb + UHAT_OFF);
    _Float16* w6 = (_Float16*)(wsb + W6_OFF);
    _Float16* h3 = (_Float16*)(wsb + H3_OFF);
    float* wT1 = (float*)(wsb + WT1_OFF);
    float* pp  = (float*)(wsb + PP_OFF);
    float* u   = (float*)(wsb + U_OFF);
    float* sp  = (float*)(wsb + SP_OFF);
    float* lg  = (float*)(wsb + L_OFF);
    float* v   = (float*)(wsb + V_OFF);

    hipMemsetAsync(pp, 0, (size_t)9216 * 256 * sizeof(float), stream);

    k_prep_w<<<dim3(256, 4), 256, 0, stream>>>(pcw, w6);
    k_transpose_w1<<<81, 256, 0, stream>>>(c1w, wT1);
    k_conv1<<<dim3(10, 256), 256, 0, stream>>>(x, wT1, c1b, h3);
    k_conv2_direct<<<dim3(1152), 256, 0, stream>>>(h3, w6, pp);
    k_sum_squash2<<<1152, 256, 0, stream>>>(pp, pcb, u);
    k_build_uhat<<<1152, 256, 0, stream>>>(u, Wd, uh);

    // iter 0: c = 0.1 exactly
    k_route_s0<<<dim3(144, 4), 256, 0, stream>>>(uh, sp);
    k_route_v<<<160, 256, 0, stream>>>(sp, v);
    // iter 1 (fused agree+softmax+s); logits were zero -> add=0, store for iter 2
    k_route_as<<<dim3(144, 4), 256, 0, stream>>>(lg, uh, v, sp, 0, 1);
    k_route_v<<<160, 256, 0, stream>>>(sp, v);
    // iter 2 (fused); last use of logits -> no store
    k_route_as<<<dim3(144, 4), 256, 0, stream>>>(lg, uh, v, sp, 1, 0);
    k_route_v<<<160, 256, 0, stream>>>(sp, out);
}

// Round 8
// 449.403 us; speedup vs baseline: 1.0752x; 1.0554x over previous
//
#include <hip/hip_runtime.h>
#include <hip/hip_bf16.h>

// ---------------- problem constants ----------------
#define NI 1152
// conv2 GEMM view: M=9216 as (pos,b)=36*256; N=256 (oc); K=81 taps x 256 ic
// Round-8: r1 skeleton (grid 1152, single pp, passed 4x) with a zero-explicit-pipeline
// conv2 inner loop + __launch_bounds__(256,4). Rationale: VGPR_Count excludes the 64
// unified-file AGPRs; r1's 3-buffer pipeline = ~152 regs/wave -> above the 128
// occupancy quantum -> 2 waves/SIMD cap. Dropping the 96 buffer VGPRs lands ~116 regs
// -> 4 waves/SIMD -> TLP (m114 implicit wave overlap) covers L2/L3 latency.

typedef __attribute__((ext_vector_type(8))) _Float16 f16x8;
typedef __attribute__((ext_vector_type(4))) float f32x4;
typedef __attribute__((ext_vector_type(8))) unsigned short u16x8;
typedef __attribute__((ext_vector_type(4))) unsigned short u16x4;

// ws layout (bytes). Phase-1 buffers (w6,h3,wT1,pp) alias under uhat (94.4MB):
static const size_t UHAT_OFF = 0;                        // bf16 1152*10*256*16 = 94,371,840
static const size_t W6_OFF   = 0;                        // f16 81*8*16*64*8 = 10,616,832 B
static const size_t H3_OFF   = 10747904UL;               // f16 8*400*4*256*8 = 52,428,800 B
static const size_t WT1_OFF  = 63176704UL;               // f32 81*256
static const size_t PP_OFF   = 63259648UL;               // f32 9216*256 (ends 72.7MB < 94.4MB)
static const size_t U_OFF    = 94371840UL;               // f32 u[i][b][d]
static const size_t SP_OFF   = 103809024UL;              // f32 144*256*160
static const size_t L_OFF    = 127401984UL;              // f32 256*1152*10
static const size_t V_OFF    = 139198464UL;              // f32 256*160

__device__ __forceinline__ unsigned short f2bf(float x) {
    unsigned u = __builtin_bit_cast(unsigned, x);
    u += 0x7fffu + ((u >> 16) & 1u);
    return (unsigned short)(u >> 16);
}
__device__ __forceinline__ float bf2f(unsigned short h) {
    return __builtin_bit_cast(float, (unsigned)h << 16);
}
__device__ __forceinline__ void atomAddF(float* p, float v) {
    __hip_atomic_fetch_add(p, v, __ATOMIC_RELAXED, __HIP_MEMORY_SCOPE_AGENT);
}

// ---------------- weight prep: pc_w [oc][ic*81+tap] -> w6 frag-linear ----------------
// w6 linear: (((tap*8+ks)*16 + og)*64 + lane)*8 + icl
//   og=oc>>4, fr=oc&15, lane=kch*16+fr, ic=ks*32+kch*8+icl
__global__ __launch_bounds__(256) void k_prep_w(const float* __restrict__ pcw,
                                                _Float16* __restrict__ w6) {
    __shared__ float sl[5184];
    int oc  = blockIdx.x;       // 256
    int ic0 = blockIdx.y * 64;  // 4 chunks
    const float* src = pcw + (size_t)oc * 20736 + (size_t)ic0 * 81;
    for (int j = threadIdx.x; j < 5184; j += 256) sl[j] = src[j];
    __syncthreads();
    int og = oc >> 4, fr = oc & 15;
    for (int t = threadIdx.x; t < 5184; t += 256) {
        int tap = t >> 6, i = t & 63;
        int ic = ic0 + i;
        int ks = ic >> 5, kch = (ic >> 3) & 3, icl = ic & 7;
        int lane = kch * 16 + fr;
        w6[(((size_t)(tap * 8 + ks) * 16 + og) * 64 + lane) * 8 + icl] =
            (_Float16)sl[i * 81 + tap];
    }
}

// conv1_w [oc][81] -> wT1 [t][oc]
__global__ void k_transpose_w1(const float* __restrict__ w, float* __restrict__ wT) {
    int t = blockIdx.x, oc = threadIdx.x;
    wT[t * 256 + oc] = w[oc * 81 + t];
}

// ---------------- conv1 + relu -> h3[ks][y][x][p][b][8] f16 ----------------
__global__ __launch_bounds__(256) void k_conv1(const float* __restrict__ x,
                                               const float* __restrict__ wT1,
                                               const float* __restrict__ bias,
                                               _Float16* __restrict__ h3) {
    __shared__ _Float16 hs[2][20][256];  // 20KB
    int b  = blockIdx.y;    // 256
    int rp = blockIdx.x;    // 10 row-pairs
    int oc = threadIdx.x;   // 256
    int oy0 = rp * 2;
    const float* xb = x + (size_t)b * 784;
    float bv = bias[oc];
    float acc0[20], acc1[20];
#pragma unroll
    for (int i = 0; i < 20; ++i) { acc0[i] = bv; acc1[i] = bv; }
    for (int ky = 0; ky < 9; ++ky) {
        const float* r0 = xb + (oy0 + ky) * 28;
        const float* r1 = r0 + 28;
        float x0[28], x1[28];
#pragma unroll
        for (int c = 0; c < 28; ++c) { x0[c] = r0[c]; x1[c] = r1[c]; }
#pragma unroll
        for (int kx = 0; kx < 9; ++kx) {
            float w = wT1[(ky * 9 + kx) * 256 + oc];
#pragma unroll
            for (int px = 0; px < 20; ++px) {
                acc0[px] += x0[px + kx] * w;
                acc1[px] += x1[px + kx] * w;
            }
        }
    }
#pragma unroll
    for (int px = 0; px < 20; ++px) {
        hs[0][px][oc] = (_Float16)fmaxf(acc0[px], 0.f);
        hs[1][px][oc] = (_Float16)fmaxf(acc1[px], 0.f);
    }
    __syncthreads();
    for (int cid = threadIdx.x; cid < 1280; cid += 256) {
        int kp = cid & 31;          // ks*4 + p
        int pos = cid >> 5;         // ry*20 + px
        int ry = pos / 20, px2 = pos % 20;
        int ks = kp >> 2, p = kp & 3;
        f16x8 val = *(const f16x8*)&hs[ry][px2][ks * 32 + p * 8];
        _Float16* dst = h3 + ((size_t)((ks * 400 + (oy0 + ry) * 20 + px2) * 4 + p) * 256 + b) * 8;
        *(f16x8*)dst = val;
    }
}

// ---------------- primary caps conv: low-register flat-load MFMA, TLP-covered ----------------
// grid 1152 flat; block 256 = 4 waves (2x2), wave tile 64x64.
// ks = blk&7 -> XCD-affinity on split-K axis (round-robin %8): per-XCD L2 set = one slice
// (proven: FETCH 257->57MB in r1).
// Zero-explicit-pipeline loop: per tap {load 8 frags, 16 MFMA}, unroll 1. With
// __launch_bounds__(256,4) the allocator fits <=128 regs/wave (est. ~52 VGPR + 64 AGPR)
// -> 4 waves/SIMD -> 4 blocks/CU resident (vs 2 for every prior >=152-reg variant).
// Latency hiding comes from cross-wave TLP (m114), not per-wave buffering: 16 waves/CU
// x 78cy MFMA-pipe demand per wave-tap saturates the matrix pipe if latency-bound.
__global__ __launch_bounds__(256, 4) void k_conv2_direct(
    const _Float16* __restrict__ h3, const _Float16* __restrict__ w6,
    float* __restrict__ pp) {
    const int blk = blockIdx.x;
    const int ks = blk & 7;          // XCD = ks (round-robin %8)
    const int rest = blk >> 3;       // 0..143
    const int mt = rest % 72;        // consecutive co-resident blocks: consecutive mt
    const int nt = rest / 72;        // same nt -> same B panel on an XCD cohort
    const int pos = mt >> 1, bhalf = mt & 1;
    const int py = pos / 6, px = pos % 6;
    const int l = threadIdx.x & 63;
    const int w = threadIdx.x >> 6;
    const int wm = w >> 1, wn = w & 1;
    const int p = l >> 4, fr = l & 15;

    // A lane base (element offsets, excl. tap window): + (y*20+x)*8192 + mi*128
    const _Float16* abase = h3 + (size_t)ks * 3276800 + p * 2048 +
                            (bhalf * 128 + wm * 64 + fr) * 8;
    // B lane base: + (tap*8+ks)*8192 + ni*512
    const _Float16* bbase = w6 + (size_t)ks * 8192 + (nt * 8 + wn * 4) * 512 + l * 8;

    f32x4 acc[4][4];
    const f32x4 z = {0.f, 0.f, 0.f, 0.f};
#pragma unroll
    for (int mi = 0; mi < 4; ++mi)
#pragma unroll
        for (int ni = 0; ni < 4; ++ni) acc[mi][ni] = z;

    int win = (2 * py) * 20 + 2 * px;  // tap-0 window plane offset
    int wx = 0;
#pragma unroll 1
    for (int t = 0; t < 81; ++t) {
        const _Float16* ab = abase + (size_t)win * 8192;
        const _Float16* bb = bbase + (size_t)t * 65536;
        f16x8 a0 = *(const f16x8*)(ab);
        f16x8 a1 = *(const f16x8*)(ab + 128);
        f16x8 a2 = *(const f16x8*)(ab + 256);
        f16x8 a3 = *(const f16x8*)(ab + 384);
        f16x8 b0 = *(const f16x8*)(bb);
        f16x8 b1 = *(const f16x8*)(bb + 512);
        f16x8 b2 = *(const f16x8*)(bb + 1024);
        f16x8 b3 = *(const f16x8*)(bb + 1536);
        __builtin_amdgcn_s_setprio(1);
        acc[0][0] = __builtin_amdgcn_mfma_f32_16x16x32_f16(a0, b0, acc[0][0], 0, 0, 0);
        acc[0][1] = __builtin_amdgcn_mfma_f32_16x16x32_f16(a0, b1, acc[0][1], 0, 0, 0);
        acc[0][2] = __builtin_amdgcn_mfma_f32_16x16x32_f16(a0, b2, acc[0][2], 0, 0, 0);
        acc[0][3] = __builtin_amdgcn_mfma_f32_16x16x32_f16(a0, b3, acc[0][3], 0, 0, 0);
        acc[1][0] = __builtin_amdgcn_mfma_f32_16x16x32_f16(a1, b0, acc[1][0], 0, 0, 0);
        acc[1][1] = __builtin_amdgcn_mfma_f32_16x16x32_f16(a1, b1, acc[1][1], 0, 0, 0);
        acc[1][2] = __builtin_amdgcn_mfma_f32_16x16x32_f16(a1, b2, acc[1][2], 0, 0, 0);
        acc[1][3] = __builtin_amdgcn_mfma_f32_16x16x32_f16(a1, b3, acc[1][3], 0, 0, 0);
        acc[2][0] = __builtin_amdgcn_mfma_f32_16x16x32_f16(a2, b0, acc[2][0], 0, 0, 0);
        acc[2][1] = __builtin_amdgcn_mfma_f32_16x16x32_f16(a2, b1, acc[2][1], 0, 0, 0);
        acc[2][2] = __builtin_amdgcn_mfma_f32_16x16x32_f16(a2, b2, acc[2][2], 0, 0, 0);
        acc[2][3] = __builtin_amdgcn_mfma_f32_16x16x32_f16(a2, b3, acc[2][3], 0, 0, 0);
        acc[3][0] = __builtin_amdgcn_mfma_f32_16x16x32_f16(a3, b0, acc[3][0], 0, 0, 0);
        acc[3][1] = __builtin_amdgcn_mfma_f32_16x16x32_f16(a3, b1, acc[3][1], 0, 0, 0);
        acc[3][2] = __builtin_amdgcn_mfma_f32_16x16x32_f16(a3, b2, acc[3][2], 0, 0, 0);
        acc[3][3] = __builtin_amdgcn_mfma_f32_16x16x32_f16(a3, b3, acc[3][3], 0, 0, 0);
        __builtin_amdgcn_s_setprio(0);
        if (wx == 8) { wx = 0; win += 12; } else { ++wx; win += 1; }
    }

    // epilogue: D[m][n], m=(lane>>4)*4+reg, n=lane&15; atomic split-K reduce
    const int row0 = (l >> 4) * 4;
    const int ncol = l & 15;
#pragma unroll
    for (int mi = 0; mi < 4; ++mi)
#pragma unroll
        for (int ni = 0; ni < 4; ++ni) {
            int n = nt * 128 + wn * 64 + ni * 16 + ncol;
#pragma unroll
            for (int reg = 0; reg < 4; ++reg) {
                int m = pos * 256 + bhalf * 128 + wm * 64 + mi * 16 + row0 + reg;
                atomAddF(&pp[(size_t)m * 256 + n], acc[mi][ni][reg]);
            }
        }
}

// ---------------- bias + primary squash -> u[i][b][d]  (pp m-order = pos*256+b) ----------------
__global__ __launch_bounds__(256) void k_sum_squash2(const float* __restrict__ pp,
                                                     const float* __restrict__ bias,
                                                     float* __restrict__ u) {
    int m = blockIdx.x * 8 + (threadIdx.x >> 5);
    int cap = threadIdx.x & 31;
    const float* p0 = pp + (size_t)m * 256 + cap * 8;
    float s[8], sq = 0.f;
#pragma unroll
    for (int d = 0; d < 8; ++d) {
        float a = p0[d] + bias[cap * 8 + d];
        sq += a * a; s[d] = a;
    }
    float scale = sq / ((1.0f + sq) * sqrtf(sq + 1e-8f));
    int pos = m >> 8, b = m & 255;
    int i = cap * 36 + pos;
    float* up = u + ((size_t)i * 256 + b) * 8;
    ((float4*)up)[0] = make_float4(scale * s[0], scale * s[1], scale * s[2], scale * s[3]);
    ((float4*)up)[1] = make_float4(scale * s[4], scale * s[5], scale * s[6], scale * s[7]);
}

// ---------------- build u_hat (bf16) [i][j][b][o] ----------------
__global__ __launch_bounds__(256) void k_build_uhat(const float* __restrict__ u,
                                                    const float* __restrict__ W,
                                                    unsigned short* __restrict__ UH) {
    __shared__ float Ws[1280];
    int i = blockIdx.x;  // 1152
    for (int t = threadIdx.x; t < 1280; t += 256) Ws[t] = W[(size_t)i * 1280 + t];
    __syncthreads();
    int b = threadIdx.x;  // 256
    const float* uptr = u + ((size_t)i * 256 + b) * 8;
    float u8[8];
    ((float4*)u8)[0] = ((const float4*)uptr)[0];
    ((float4*)u8)[1] = ((const float4*)uptr)[1];
#pragma unroll
    for (int j = 0; j < 10; ++j) {
        float o16[16];
#pragma unroll
        for (int o = 0; o < 16; ++o) o16[o] = 0.f;
#pragma unroll
        for (int d = 0; d < 8; ++d) {
            const float* wp = Ws + d * 160 + j * 16;
#pragma unroll
            for (int o = 0; o < 16; ++o) o16[o] += u8[d] * wp[o];
        }
        u16x8 h0, h1;
#pragma unroll
        for (int o = 0; o < 8; ++o) { h0[o] = f2bf(o16[o]); h1[o] = f2bf(o16[8 + o]); }
        unsigned short* dst = UH + ((size_t)(i * 10 + j) * 256 + b) * 16;
        *(u16x8*)dst = h0;
        *(u16x8*)(dst + 8) = h1;
    }
}

// ---------------- routing iter 0: s0 = 0.1 * sum_i u_hat ----------------
__global__ __launch_bounds__(256) void k_route_s0(const unsigned short* __restrict__ UH,
                                                  float* __restrict__ SP) {
    int it = blockIdx.x, bt = blockIdx.y;
    int b0 = bt * 64, i0 = it * 8;
    int b_l = threadIdx.x & 63;
    int og = __builtin_amdgcn_readfirstlane((int)(threadIdx.x >> 6));
    float acc[10][4];
#pragma unroll
    for (int j = 0; j < 10; ++j)
#pragma unroll
        for (int o = 0; o < 4; ++o) acc[j][o] = 0.f;
    for (int li = 0; li < 8; ++li) {
        const unsigned short* up = UH + ((size_t)(i0 + li) * 10 * 256 + b0 + b_l) * 16 + og * 4;
#pragma unroll
        for (int j = 0; j < 10; ++j) {
            u16x4 t = *(const u16x4*)(up + j * 4096);
#pragma unroll
            for (int o = 0; o < 4; ++o) acc[j][o] += bf2f(t[o]);
        }
    }
    float* sp = SP + ((size_t)it * 256 + b0 + b_l) * 160 + og * 4;
#pragma unroll
    for (int j = 0; j < 10; ++j)
        *(float4*)(sp + j * 16) = make_float4(0.1f * acc[j][0], 0.1f * acc[j][1],
                                              0.1f * acc[j][2], 0.1f * acc[j][3]);
}

// ---------------- fused routing: logits (+)= <u_hat,v>; softmax; s-partials ----------------
// grid (144,4); block 256. add=0: L := agreement (prior logits zero). storeL: write L back.
__global__ __launch_bounds__(256) void k_route_as(float* __restrict__ L,
                                                  const unsigned short* __restrict__ UH,
                                                  const float* __restrict__ V,
                                                  float* __restrict__ SP,
                                                  int add, int storeL) {
    __shared__ float VL[64][165];
    __shared__ float LG[64][81];
    int it = blockIdx.x, bt = blockIdx.y;
    int b0 = bt * 64, i0 = it * 8;
    int b_l = threadIdx.x & 63;
    int ig = __builtin_amdgcn_readfirstlane((int)(threadIdx.x >> 6));
    int b_r = threadIdx.x >> 2, part = threadIdx.x & 3;
    {
        const float4* vsrc = (const float4*)(V + (size_t)(b0 + b_r) * 160 + part * 40);
#pragma unroll
        for (int q = 0; q < 10; ++q) {
            float4 vv = vsrc[q]; int c = part * 40 + q * 4;
            VL[b_r][c] = vv.x; VL[b_r][c + 1] = vv.y; VL[b_r][c + 2] = vv.z; VL[b_r][c + 3] = vv.w;
        }
        if (add) {
            const float4* lsrc = (const float4*)(L + (size_t)(b0 + b_r) * 11520 + i0 * 10 + part * 20);
#pragma unroll
            for (int q = 0; q < 5; ++q) {
                float4 t = lsrc[q]; int c = part * 20 + q * 4;
                LG[b_r][c] = t.x; LG[b_r][c + 1] = t.y; LG[b_r][c + 2] = t.z; LG[b_r][c + 3] = t.w;
            }
        }
    }
    __syncthreads();
    // agreement phase: thread group ig handles 2 i's
#pragma unroll
    for (int ii = 0; ii < 2; ++ii) {
        int il = ig * 2 + ii;
        int i = i0 + il;
        const unsigned short* up = UH + ((size_t)i * 10 * 256 + b0 + b_l) * 16;
#pragma unroll
        for (int j = 0; j < 10; ++j) {
            u16x8 ua = *(const u16x8*)(up + j * 4096);
            u16x8 ub = *(const u16x8*)(up + j * 4096 + 8);
            float a = 0.f;
#pragma unroll
            for (int o = 0; o < 8; ++o) a += bf2f(ua[o]) * VL[b_l][j * 16 + o];
#pragma unroll
            for (int o = 0; o < 8; ++o) a += bf2f(ub[o]) * VL[b_l][j * 16 + 8 + o];
            float base = add ? LG[b_l][il * 10 + j] : 0.f;
            LG[b_l][il * 10 + j] = base + a;
        }
    }
    __syncthreads();
    if (storeL) {
        float4* ldst = (float4*)(L + (size_t)(b0 + b_r) * 11520 + i0 * 10 + part * 20);
#pragma unroll
        for (int q = 0; q < 5; ++q) {
            int c = part * 20 + q * 4;
            ldst[q] = make_float4(LG[b_r][c], LG[b_r][c + 1], LG[b_r][c + 2], LG[b_r][c + 3]);
        }
    }
    // s phase: softmax of fresh logits, accumulate c * u_hat (og = ig reuse)
    float acc[10][4];
#pragma unroll
    for (int j = 0; j < 10; ++j)
#pragma unroll
        for (int o = 0; o < 4; ++o) acc[j][o] = 0.f;
    for (int li = 0; li < 8; ++li) {
        float lg[10];
#pragma unroll
        for (int j = 0; j < 10; ++j) lg[j] = LG[b_l][li * 10 + j];
        float m = lg[0];
#pragma unroll
        for (int j = 1; j < 10; ++j) m = fmaxf(m, lg[j]);
        float e[10], ssum = 0.f;
#pragma unroll
        for (int j = 0; j < 10; ++j) { e[j] = __expf(lg[j] - m); ssum += e[j]; }
        float inv = 1.0f / ssum;
        const unsigned short* up = UH + ((size_t)(i0 + li) * 10 * 256 + b0 + b_l) * 16 + ig * 4;
#pragma unroll
        for (int j = 0; j < 10; ++j) {
            float cj = e[j] * inv;
            u16x4 t = *(const u16x4*)(up + j * 4096);
#pragma unroll
            for (int o = 0; o < 4; ++o) acc[j][o] += cj * bf2f(t[o]);
        }
    }
    float* sp = SP + ((size_t)it * 256 + b0 + b_l) * 160 + ig * 4;
#pragma unroll
    for (int j = 0; j < 10; ++j)
        *(float4*)(sp + j * 16) = make_float4(acc[j][0], acc[j][1], acc[j][2], acc[j][3]);
}

// ---------------- routing: reduce partials + squash -> v ----------------
__global__ __launch_bounds__(256) void k_route_v(const float* __restrict__ SP,
                                                 float* __restrict__ vout) {
    int n = blockIdx.x * 256 + threadIdx.x;  // 40960
    float ssum = 0.f;
    for (int t = 0; t < 144; ++t) ssum += SP[(size_t)t * 40960 + n];
    float sq = ssum * ssum;
    float tot = sq;
#pragma unroll
    for (int mask = 1; mask < 16; mask <<= 1) tot += __shfl_xor(tot, mask, 64);
    float scale = tot / ((1.0f + tot) * sqrtf(tot + 1e-8f));
    vout[n] = scale * ssum;
}

// ---------------- launcher ----------------
extern "C" void kernel_launch(void* const* d_in, const int* in_sizes, int n_in,
                              void* d_out, int out_size, void* d_ws, size_t ws_size,
                              hipStream_t stream) {
    (void)in_sizes; (void)n_in; (void)out_size; (void)ws_size;
    const float* x   = (const float*)d_in[0];
    const float* c1w = (const float*)d_in[1];
    const float* c1b = (const float*)d_in[2];
    const float* pcw = (const float*)d_in[3];
    const float* pcb = (const float*)d_in[4];
    const float* Wd  = (const float*)d_in[5];
    float* out = (float*)d_out;
    char* wsb  = (char*)d_ws;

    unsigned short* uh = (unsigned short*)(wsb + UHAT_OFF);
    _Float16* w6 = (_Float16*)(wsb + W6_OFF);
    _Float16* h3 = (_Float16*)(wsb + H3_OFF);
    float* wT1 = (float*)(wsb + WT1_OFF);
    float* pp  = (float*)(wsb + PP_OFF);
    float* u   = (float*)(wsb + U_OFF);
    float* sp  = (float*)(wsb + SP_OFF);
    float* lg  = (float*)(wsb + L_OFF);
    float* v   = (float*)(wsb + V_OFF);

    hipMemsetAsync(pp, 0, (size_t)9216 * 256 * sizeof(float), stream);

    k_prep_w<<<dim3(256, 4), 256, 0, stream>>>(pcw, w6);
    k_transpose_w1<<<81, 256, 0, stream>>>(c1w, wT1);
    k_conv1<<<dim3(10, 256), 256, 0, stream>>>(x, wT1, c1b, h3);
    k_conv2_direct<<<dim3(1152), 256, 0, stream>>>(h3, w6, pp);
    k_sum_squash2<<<1152, 256, 0, stream>>>(pp, pcb, u);
    k_build_uhat<<<1152, 256, 0, stream>>>(u, Wd, uh);

    // iter 0: c = 0.1 exactly
    k_route_s0<<<dim3(144, 4), 256, 0, stream>>>(uh, sp);
    k_route_v<<<160, 256, 0, stream>>>(sp, v);
    // iter 1 (fused agree+softmax+s); logits were zero -> add=0, store for iter 2
    k_route_as<<<dim3(144, 4), 256, 0, stream>>>(lg, uh, v, sp, 0, 1);
    k_route_v<<<160, 256, 0, stream>>>(sp, v);
    // iter 2 (fused); last use of logits -> no store
    k_route_as<<<dim3(144, 4), 256, 0, stream>>>(lg, uh, v, sp, 1, 0);
    k_route_v<<<160, 256, 0, stream>>>(sp, out);
}